// Round 1
// 883.437 us; speedup vs baseline: 1.0413x; 1.0413x over previous
//
#include <hip/hip_runtime.h>
#include <math.h>

// ============================================================================
// MixtralDecoderLayer on MI355X — Round 5: fused w1+w3 MoE GEMM.
//
// Change vs round 4: the two grouped MoE GEMMs (x@w3 -> hg3; silu(x@w1)*hg3)
// are fused into one kernel k_moe_w13. Each block stages A + B1 + B3 tiles
// (48 KB LDS, double-buffered) and runs 32 MFMAs per k-step into two
// accumulators -> 2x matrix work amortized per barrier drain (the measured
// stall: MfmaUtil 13%, all pipes idle). Epilogue computes silu(acc1)*acc3
// directly, eliminating the hg3 HBM round-trip (58 MB) and one dispatch.
// Blocks are swizzled so the 4 m-blocks sharing a (expert, n0) B-panel land
// on the same XCD adjacent in schedule order -> B-panel L2 reuse (FETCH was
// 134 MB vs 59 MB ideal).
// ============================================================================

typedef unsigned short u16;
typedef unsigned int u32;
typedef __attribute__((ext_vector_type(8))) short s16x8;
typedef __attribute__((ext_vector_type(8))) _Float16 f16x8;
typedef __attribute__((ext_vector_type(4))) float f32x4;

#define S_LEN 2048
#define HDIM  1024
#define NHEAD 16
#define NKVH  4
#define HD    64
#define ISZ   3584
#define NEXP  8
#define NSLOT 4096
#define EPS_F 1e-5f
#define NEG_INF -1e30f
#define LOG2E 1.44269504f

__device__ __forceinline__ float bf2f(u16 u) {
    union { u32 i; float f; } c; c.i = ((u32)u) << 16; return c.f;
}
__device__ __forceinline__ u16 f2bf(float f) {
    union { float f; u32 i; } c; c.f = f;
    u32 r = (c.i + 0x7fffu + ((c.i >> 16) & 1u)) >> 16;
    return (u16)r;
}
__device__ __forceinline__ u16 f2h_bits(float f) {
    union { _Float16 h; u16 u; } c; c.h = (_Float16)f; return c.u;
}
__device__ __forceinline__ void async16(const u16* g, u16* l) {
    __builtin_amdgcn_global_load_lds(
        (const __attribute__((address_space(1))) void*)g,
        (__attribute__((address_space(3))) void*)l, 16, 0, 0);
}

// ---------------------------------------------------------------------------
__global__ void k_zero_ints(int* __restrict__ p, int n) {
    int i = blockIdx.x * blockDim.x + threadIdx.x;
    if (i < n) p[i] = 0;
}

// ---------------------------------------------------------------------------
__global__ __launch_bounds__(256)
void k_rmsnorm_bf(const float* __restrict__ x, const float* __restrict__ w,
                  u16* __restrict__ out) {
    int t = blockIdx.x;
    int tid = threadIdx.x;
    float4 v = ((const float4*)(x + (size_t)t * HDIM))[tid];
    float ss = v.x * v.x + v.y * v.y + v.z * v.z + v.w * v.w;
#pragma unroll
    for (int off = 32; off >= 1; off >>= 1) ss += __shfl_xor(ss, off, 64);
    __shared__ float red[4];
    if ((tid & 63) == 0) red[tid >> 6] = ss;
    __syncthreads();
    float tot = red[0] + red[1] + red[2] + red[3];
    float rstd = rsqrtf(tot * (1.0f / HDIM) + EPS_F);
    float4 wv = ((const float4*)w)[tid];
    uint2 pk;
    pk.x = (u32)f2bf(v.x * rstd * wv.x) | ((u32)f2bf(v.y * rstd * wv.y) << 16);
    pk.y = (u32)f2bf(v.z * rstd * wv.z) | ((u32)f2bf(v.w * rstd * wv.w) << 16);
    ((uint2*)(out + (size_t)t * HDIM))[tid] = pk;
}

// ---------------------------------------------------------------------------
// Transpose + convert: src fp32 [R][C] -> dst bf16 [C][R].
__global__ __launch_bounds__(256)
void k_cvt_t(const float* __restrict__ src, u16* __restrict__ dst,
             int R, int C, long long srcZ, long long dstZ) {
    const int z = blockIdx.z;
    src += (size_t)z * srcZ;
    dst += (size_t)z * dstZ;
    const int lane = threadIdx.x & 63, w = threadIdx.x >> 6;
    const int c = blockIdx.x * 64 + lane;
    const int r0 = blockIdx.y * 128 + w * 32;
    float v[32];
#pragma unroll
    for (int i = 0; i < 32; i++) v[i] = src[(size_t)(r0 + i) * C + c];
#pragma unroll
    for (int g = 0; g < 4; g++) {
        uint4 pk;
        pk.x = (u32)f2bf(v[g * 8 + 0]) | ((u32)f2bf(v[g * 8 + 1]) << 16);
        pk.y = (u32)f2bf(v[g * 8 + 2]) | ((u32)f2bf(v[g * 8 + 3]) << 16);
        pk.z = (u32)f2bf(v[g * 8 + 4]) | ((u32)f2bf(v[g * 8 + 5]) << 16);
        pk.w = (u32)f2bf(v[g * 8 + 6]) | ((u32)f2bf(v[g * 8 + 7]) << 16);
        *(uint4*)(&dst[(size_t)c * R + r0 + g * 8]) = pk;
    }
}

// ---------------------------------------------------------------------------
// Stage one 128x32 A-tile + 128x32 B-tile (bf16) into `buf` via async16.
__device__ __forceinline__ void stage32(const u16* __restrict__ A,
                                        const u16* __restrict__ Bt, int K,
                                        int rowA0, int rowAmax, int n0, int kc,
                                        u16* buf, int wid, int sr, int sc) {
#pragma unroll
    for (int t = 0; t < 2; t++) {
        int row = wid * 32 + t * 16 + sr;
        int ck = (sc ^ (row & 3)) << 3;
        int ra = rowA0 + row;
        if (ra > rowAmax) ra = rowAmax;
        u16* ldsA = buf + (wid * 32 + t * 16) * 32;
        async16(A + (size_t)ra * K + kc + ck, ldsA);
        async16(Bt + (size_t)(n0 + row) * K + kc + ck, ldsA + 4096);
    }
}

// Fused variant: stage A + B1 + B3 tiles (buffer stride 12288 elems).
__device__ __forceinline__ void stage32_w13(const u16* __restrict__ A,
                                            const u16* __restrict__ B1,
                                            const u16* __restrict__ B3, int K,
                                            int rowA0, int rowAmax, int n0,
                                            int kc, u16* buf, int wid, int sr,
                                            int sc) {
#pragma unroll
    for (int t = 0; t < 2; t++) {
        int row = wid * 32 + t * 16 + sr;
        int ck = (sc ^ (row & 3)) << 3;
        int ra = rowA0 + row;
        if (ra > rowAmax) ra = rowAmax;
        u16* ldsA = buf + (wid * 32 + t * 16) * 32;
        async16(A + (size_t)ra * K + kc + ck, ldsA);
        async16(B1 + (size_t)(n0 + row) * K + kc + ck, ldsA + 4096);
        async16(B3 + (size_t)(n0 + row) * K + kc + ck, ldsA + 8192);
    }
}

// ---------------------------------------------------------------------------
// Double-buffered MFMA GEMM core: C[128,128] += A[rows,kbeg:kend] @ Bt^T.
// lds must be 16384 u16 (32 KB): two 8192-elem buffers (A @0, B @4096 each).
__device__ __forceinline__ void gemm128_dbuf(
    const u16* __restrict__ A, const u16* __restrict__ Bt, int K,
    int kbeg, int kend, int rowA0, int rowAmax, int n0,
    u16* lds, f32x4 acc[4][4]) {
    const int tid = threadIdx.x;
    const int lane = tid & 63, wid = tid >> 6;
    const int sr = lane >> 2, sc = lane & 3;
    const int ln = lane & 15, q = lane >> 4;
    const int wm = wid >> 1, wn = wid & 1;
    stage32(A, Bt, K, rowA0, rowAmax, n0, kbeg, lds, wid, sr, sc);
    int pp = 0;
    for (int kc = kbeg; kc < kend; kc += 32) {
        u16* cur = lds + pp * 8192;
        u16* nxt = lds + (pp ^ 1) * 8192;
        pp ^= 1;
        __syncthreads();   // drains vmcnt -> stage(kc) done; stage was issued
                           // one compute-phase ago, so latency is overlapped
        if (kc + 32 < kend)
            stage32(A, Bt, K, rowA0, rowAmax, n0, kc + 32, nxt, wid, sr, sc);
        s16x8 af[4], bfv[4];
#pragma unroll
        for (int i = 0; i < 4; i++) {
            int ar = wm * 64 + i * 16 + ln;
            af[i] = *(const s16x8*)(cur + ar * 32 + ((q ^ (ar & 3)) << 3));
            int br = wn * 64 + i * 16 + ln;
            bfv[i] = *(const s16x8*)(cur + 4096 + br * 32 + ((q ^ (br & 3)) << 3));
        }
#pragma unroll
        for (int i = 0; i < 4; i++)
#pragma unroll
            for (int j = 0; j < 4; j++)
                acc[i][j] = __builtin_amdgcn_mfma_f32_16x16x32_bf16(
                    af[i], bfv[j], acc[i][j], 0, 0, 0);
    }
}

// ---------------------------------------------------------------------------
// Flat GEMM.  mode 0: fp32->F0 | 1: bf16->O16 | 2: fp32+RES->F0 |
//             3: qkv split -> F0(q fp32) F1(k fp32) O16(v fp16 bits)
__global__ __launch_bounds__(256, 2)
void k_gemm_bt(const u16* __restrict__ A, const u16* __restrict__ Bt,
               int M, int N, int K, int mode,
               float* __restrict__ F0, float* __restrict__ F1,
               const float* __restrict__ RES, u16* __restrict__ O16) {
    __shared__ u16 lds[16384];
    const int m0 = blockIdx.y * 128, n0 = blockIdx.x * 128;
    f32x4 acc[4][4];
#pragma unroll
    for (int i = 0; i < 4; i++)
#pragma unroll
        for (int j = 0; j < 4; j++) acc[i][j] = (f32x4){0.f, 0.f, 0.f, 0.f};
    gemm128_dbuf(A, Bt, K, 0, K, m0, M - 1, n0, lds, acc);
    const int lane = threadIdx.x & 63, wid = threadIdx.x >> 6;
    const int ln = lane & 15, q = lane >> 4, wm = wid >> 1, wn = wid & 1;
#pragma unroll
    for (int i = 0; i < 4; i++) {
#pragma unroll
        for (int r = 0; r < 4; r++) {
            int m = m0 + wm * 64 + i * 16 + q * 4 + r;
#pragma unroll
            for (int j = 0; j < 4; j++) {
                int n = n0 + wn * 64 + j * 16 + ln;
                float v = acc[i][j][r];
                if (mode == 0) {
                    F0[(size_t)m * N + n] = v;
                } else if (mode == 1) {
                    O16[(size_t)m * N + n] = f2bf(v);
                } else if (mode == 2) {
                    F0[(size_t)m * N + n] = v + RES[(size_t)m * N + n];
                } else {
                    if (n < 1024)       F0[(size_t)m * 1024 + n] = v;
                    else if (n < 1280)  F1[(size_t)m * 256 + (n - 1024)] = v;
                    else                O16[(size_t)m * 256 + (n - 1280)] = f2h_bits(v);
                }
            }
        }
    }
}

// ---------------------------------------------------------------------------
// Fused grouped MoE GEMM: He = silu(Xg @ w1^T) * (Xg @ w3^T), per expert.
// One block computes a 128x128 tile of BOTH products: stages A + B1 + B3
// (48 KB LDS dbuf), 32 MFMA per k-step -> 2x matrix work per barrier drain.
// Block swizzle: the 16 m-blocks of a (e, n0) group get ids == same mod 8
// (same XCD) and adjacent per-XCD order -> B-panel fetched ~once per group.
__global__ __launch_bounds__(256, 2)
void k_moe_w13(const u16* __restrict__ Xg, const u16* __restrict__ W1T,
               const u16* __restrict__ W3T, u16* __restrict__ He,
               const int* __restrict__ offs) {
    // flat 1D grid of 28*16*8 = 3584 blocks
    const int bid = blockIdx.x;
    const int xcd = bid & 7;
    const int r_ = bid >> 3;          // 0..447
    const int mb = r_ & 15;           // m-block, innermost on each XCD
    const int gslot = r_ >> 4;        // 0..27
    const int gid = gslot * 8 + xcd;  // 0..223 group = (expert, n-block)
    const int e = gid / 28;
    const int nb = gid - e * 28;
    const int base = offs[e], cnt = offs[e + 1] - base;
    const int m0 = mb * 128;
    if (m0 >= cnt) return;
    __shared__ u16 lds[24576];        // 2 buffers x (A,B1,B3) x 4096 elems
    const u16* B1 = W1T + (size_t)e * ISZ * HDIM;
    const u16* B3 = W3T + (size_t)e * ISZ * HDIM;
    const int n0 = nb * 128;
    f32x4 acc1[4][4], acc3[4][4];
#pragma unroll
    for (int i = 0; i < 4; i++)
#pragma unroll
        for (int j = 0; j < 4; j++) {
            acc1[i][j] = (f32x4){0.f, 0.f, 0.f, 0.f};
            acc3[i][j] = (f32x4){0.f, 0.f, 0.f, 0.f};
        }
    const int tid = threadIdx.x;
    const int lane = tid & 63, wid = tid >> 6;
    const int sr = lane >> 2, sc = lane & 3;
    const int ln = lane & 15, q = lane >> 4;
    const int wm = wid >> 1, wn = wid & 1;
    const int rowA0 = base + m0;
    stage32_w13(Xg, B1, B3, HDIM, rowA0, NSLOT - 1, n0, 0, lds, wid, sr, sc);
    int pp = 0;
    for (int kc = 0; kc < HDIM; kc += 32) {
        u16* cur = lds + pp * 12288;
        u16* nxt = lds + (pp ^ 1) * 12288;
        pp ^= 1;
        __syncthreads();
        if (kc + 32 < HDIM)
            stage32_w13(Xg, B1, B3, HDIM, rowA0, NSLOT - 1, n0, kc + 32, nxt,
                        wid, sr, sc);
        s16x8 af[4], b1f[4], b3f[4];
#pragma unroll
        for (int i = 0; i < 4; i++) {
            int ar = wm * 64 + i * 16 + ln;
            af[i] = *(const s16x8*)(cur + ar * 32 + ((q ^ (ar & 3)) << 3));
            int br = wn * 64 + i * 16 + ln;
            int bo = br * 32 + ((q ^ (br & 3)) << 3);
            b1f[i] = *(const s16x8*)(cur + 4096 + bo);
            b3f[i] = *(const s16x8*)(cur + 8192 + bo);
        }
#pragma unroll
        for (int i = 0; i < 4; i++)
#pragma unroll
            for (int j = 0; j < 4; j++) {
                acc1[i][j] = __builtin_amdgcn_mfma_f32_16x16x32_bf16(
                    af[i], b1f[j], acc1[i][j], 0, 0, 0);
                acc3[i][j] = __builtin_amdgcn_mfma_f32_16x16x32_bf16(
                    af[i], b3f[j], acc3[i][j], 0, 0, 0);
            }
    }
    // epilogue: silu(acc1) * acc3 -> He (bf16)
#pragma unroll
    for (int i = 0; i < 4; i++) {
#pragma unroll
        for (int r = 0; r < 4; r++) {
            int mloc = wm * 64 + i * 16 + q * 4 + r;
            if (m0 + mloc >= cnt) continue;
            size_t row = (size_t)(base + m0 + mloc);
#pragma unroll
            for (int j = 0; j < 4; j++) {
                int n = n0 + wn * 64 + j * 16 + ln;
                float v1 = acc1[i][j][r];
                float v3 = acc3[i][j][r];
                float s = v1 / (1.0f + expf(-v1));
                He[row * ISZ + n] = f2bf(s * v3);
            }
        }
    }
}

// ---------------------------------------------------------------------------
// MoE w2 GEMM, split-K=2: z = e + 8*half; half 0 -> OA, half 1 -> OB (fp32).
__global__ __launch_bounds__(256, 2)
void k_moe_w2(const u16* __restrict__ He, const u16* __restrict__ W2T,
              float* __restrict__ OA, float* __restrict__ OB,
              const int* __restrict__ offs) {
    const int z = blockIdx.z;
    const int e = z & 7, half = z >> 3;
    const int base = offs[e], cnt = offs[e + 1] - base;
    const int m0 = blockIdx.y * 128;
    if (m0 >= cnt) return;
    __shared__ u16 lds[16384];
    const u16* Bt = W2T + (size_t)e * HDIM * ISZ;
    const int n0 = blockIdx.x * 128;
    f32x4 acc[4][4];
#pragma unroll
    for (int i = 0; i < 4; i++)
#pragma unroll
        for (int j = 0; j < 4; j++) acc[i][j] = (f32x4){0.f, 0.f, 0.f, 0.f};
    gemm128_dbuf(He, Bt, ISZ, half * (ISZ / 2), (half + 1) * (ISZ / 2),
                 base + m0, NSLOT - 1, n0, lds, acc);
    float* F0 = half ? OB : OA;
    const int lane = threadIdx.x & 63, wid = threadIdx.x >> 6;
    const int ln = lane & 15, q = lane >> 4, wm = wid >> 1, wn = wid & 1;
#pragma unroll
    for (int i = 0; i < 4; i++) {
#pragma unroll
        for (int r = 0; r < 4; r++) {
            int mloc = wm * 64 + i * 16 + q * 4 + r;
            if (m0 + mloc >= cnt) continue;
            size_t row = (size_t)(base + m0 + mloc);
#pragma unroll
            for (int j = 0; j < 4; j++) {
                int n = n0 + wn * 64 + j * 16 + ln;
                F0[row * HDIM + n] = acc[i][j][r];
            }
        }
    }
}

// ---------------------------------------------------------------------------
// RoPE + convert to fp16 bits.
__global__ __launch_bounds__(256)
void k_rope_cvt(const float* __restrict__ q, const float* __restrict__ k,
                const int* __restrict__ pos, u16* __restrict__ qb2,
                u16* __restrict__ kb2) {
    int id = blockIdx.x * blockDim.x + threadIdx.x;
    int d = id & 31;
    int hh = (id >> 5) % (NHEAD + NKVH);
    int s = id / ((NHEAD + NKVH) * 32);
    float p = (float)pos[s];
    float inv = exp2f(-((float)(2 * d) / (float)HD) * log2f(1.0e6f));
    float ang = p * inv;
    float c = cosf(ang), sn = sinf(ang);
    const float* sp; u16* dp;
    if (hh < NHEAD) {
        sp = q + (size_t)s * (NHEAD * HD) + hh * HD;
        dp = qb2 + (size_t)s * (NHEAD * HD) + hh * HD;
    } else {
        sp = k + (size_t)s * (NKVH * HD) + (hh - NHEAD) * HD;
        dp = kb2 + (size_t)s * (NKVH * HD) + (hh - NHEAD) * HD;
    }
    float x1 = sp[d], x2 = sp[d + 32];
    dp[d]      = f2h_bits(x1 * c - x2 * sn);
    dp[d + 32] = f2h_bits(x2 * c + x1 * sn);
}

// ---------------------------------------------------------------------------
// MFMA flash attention (fp16 inputs, fp32 accumulate). Round-3-verified.
__global__ __launch_bounds__(256)
void k_attn_mfma(const u16* __restrict__ qb, const u16* __restrict__ kb,
                 const u16* __restrict__ vb, u16* __restrict__ ob) {
    __shared__ u16 Qs[64 * 64];
    __shared__ u16 Ks[64 * 64];
    __shared__ u16 Vt[64 * 64];
    __shared__ u16 Ps[64 * 64];
    const int qt = blockIdx.x, h = blockIdx.y, kvh = h >> 2;
    const int tid = threadIdx.x, lane = tid & 63, w = tid >> 6;
    const int ln = lane & 15, quad = lane >> 4;

#pragma unroll
    for (int p = 0; p < 2; p++) {
        int r = p * 32 + (tid >> 3), c = tid & 7;
        uint4 v = *(const uint4*)(qb + (size_t)(qt * 64 + r) * (NHEAD * HD) +
                                  h * HD + c * 8);
        *(uint4*)&Qs[r * 64 + ((c ^ (r & 7)) << 3)] = v;
    }

    float m_[4], l_[4];
    f32x4 Oa[4];
#pragma unroll
    for (int r = 0; r < 4; r++) { m_[r] = NEG_INF; l_[r] = 0.0f; }
#pragma unroll
    for (int nt = 0; nt < 4; nt++) Oa[nt] = (f32x4){0.f, 0.f, 0.f, 0.f};

    for (int kt = 0; kt <= qt; kt++) {
        __syncthreads();
#pragma unroll
        for (int p = 0; p < 2; p++) {
            int r = p * 32 + (tid >> 3), c = tid & 7;
            uint4 v = *(const uint4*)(kb + (size_t)(kt * 64 + r) * (NKVH * HD) +
                                      kvh * HD + c * 8);
            *(uint4*)&Ks[r * 64 + ((c ^ (r & 7)) << 3)] = v;
        }
        {
            int s = tid & 63;
#pragma unroll
            for (int half = 0; half < 2; half++) {
                int d0 = w * 16 + half * 8;
                uint4 v = *(const uint4*)(vb + (size_t)(kt * 64 + s) * (NKVH * HD) +
                                          kvh * HD + d0);
                u16 a[8];
                a[0] = (u16)(v.x & 0xffff); a[1] = (u16)(v.x >> 16);
                a[2] = (u16)(v.y & 0xffff); a[3] = (u16)(v.y >> 16);
                a[4] = (u16)(v.z & 0xffff); a[5] = (u16)(v.z >> 16);
                a[6] = (u16)(v.w & 0xffff); a[7] = (u16)(v.w >> 16);
#pragma unroll
                for (int j = 0; j < 8; j++) {
                    int d = d0 + j;
                    Vt[d * 64 + (((s >> 3) ^ (d & 7)) << 3) + (s & 7)] = a[j];
                }
            }
        }
        __syncthreads();

        f32x4 sc[4];
#pragma unroll
        for (int nt = 0; nt < 4; nt++) sc[nt] = (f32x4){0.f, 0.f, 0.f, 0.f};
#pragma unroll
        for (int ks = 0; ks < 2; ks++) {
            int arow = 16 * w + ln;
            f16x8 af = *(const f16x8*)&Qs[arow * 64 +
                                          (((ks * 4 + quad) ^ (arow & 7)) << 3)];
#pragma unroll
            for (int nt = 0; nt < 4; nt++) {
                int brow = nt * 16 + ln;
                f16x8 bf = *(const f16x8*)&Ks[brow * 64 +
                                              (((ks * 4 + quad) ^ (brow & 7)) << 3)];
                sc[nt] = __builtin_amdgcn_mfma_f32_16x16x32_f16(af, bf, sc[nt],
                                                                0, 0, 0);
            }
        }

        const bool diag = (kt == qt);
        float mt[4];
#pragma unroll
        for (int r = 0; r < 4; r++) {
            int qrow = quad * 4 + r + 16 * w;
#pragma unroll
            for (int nt = 0; nt < 4; nt++) {
                float s = sc[nt][r] * 0.125f;
                if (diag && (nt * 16 + ln) > qrow) s = NEG_INF;
                sc[nt][r] = s;
            }
            mt[r] = fmaxf(fmaxf(sc[0][r], sc[1][r]), fmaxf(sc[2][r], sc[3][r]));
        }
#pragma unroll
        for (int off = 8; off >= 1; off >>= 1)
#pragma unroll
            for (int r = 0; r < 4; r++)
                mt[r] = fmaxf(mt[r], __shfl_xor(mt[r], off, 64));

        float rs[4];
#pragma unroll
        for (int r = 0; r < 4; r++) {
            float mn = fmaxf(m_[r], mt[r]);
            float al = exp2f((m_[r] - mn) * LOG2E);
            m_[r] = mn;
            float acc0 = 0.0f;
#pragma unroll
            for (int nt = 0; nt < 4; nt++) {
                float pv = exp2f((sc[nt][r] - mn) * LOG2E);
                sc[nt][r] = pv;
                acc0 += pv;
            }
            rs[r] = acc0;
            l_[r] *= al;
#pragma unroll
            for (int nt = 0; nt < 4; nt++) Oa[nt][r] *= al;
        }
#pragma unroll
        for (int off = 8; off >= 1; off >>= 1)
#pragma unroll
            for (int r = 0; r < 4; r++) rs[r] += __shfl_xor(rs[r], off, 64);
#pragma unroll
        for (int r = 0; r < 4; r++) l_[r] += rs[r];

#pragma unroll
        for (int r = 0; r < 4; r++) {
            int row = 16 * w + quad * 4 + r;
#pragma unroll
            for (int nt = 0; nt < 4; nt++) {
                int ch = nt * 2 + (ln >> 3);
                Ps[row * 64 + ((ch ^ (row & 7)) << 3) + (ln & 7)] =
                    f2h_bits(sc[nt][r]);
            }
        }
        __syncthreads();

#pragma unroll
        for (int ks = 0; ks < 2; ks++) {
            int arow = 16 * w + ln;
            f16x8 pf = *(const f16x8*)&Ps[arow * 64 +
                                          (((ks * 4 + quad) ^ (arow & 7)) << 3)];
#pragma unroll
            for (int nt = 0; nt < 4; nt++) {
                int vrow = nt * 16 + ln;
                f16x8 vf = *(const f16x8*)&Vt[vrow * 64 +
                                              (((ks * 4 + quad) ^ (vrow & 7)) << 3)];
                Oa[nt] = __builtin_amdgcn_mfma_f32_16x16x32_f16(pf, vf, Oa[nt],
                                                                0, 0, 0);
            }
        }
    }

#pragma unroll
    for (int r = 0; r < 4; r++) {
        float inv = 1.0f / l_[r];
        int sg = qt * 64 + 16 * w + quad * 4 + r;
#pragma unroll
        for (int nt = 0; nt < 4; nt++) {
            int d = nt * 16 + ln;
            ob[(size_t)sg * HDIM + h * HD + d] = f2bf(Oa[nt][r] * inv);
        }
    }
}

// ---------------------------------------------------------------------------
__global__ __launch_bounds__(64)
void k_gate(const float* __restrict__ Hst, const float* __restrict__ PW,
            const float* __restrict__ GW, int* __restrict__ cnt,
            int* __restrict__ top_i, float* __restrict__ top_w) {
    int t = blockIdx.x;
    int lane = threadIdx.x;
    const float* hrow = Hst + (size_t)t * HDIM;
    float ss = 0.0f;
    float acc[NEXP] = {};
    for (int hh = lane; hh < HDIM; hh += 64) {
        float hv = hrow[hh];
        ss += hv * hv;
        float xw = hv * PW[hh];
        const float* g = GW + (size_t)hh * NEXP;
#pragma unroll
        for (int e = 0; e < NEXP; e++) acc[e] += xw * g[e];
    }
#pragma unroll
    for (int off = 32; off >= 1; off >>= 1) {
        ss += __shfl_xor(ss, off, 64);
#pragma unroll
        for (int e = 0; e < NEXP; e++) acc[e] += __shfl_xor(acc[e], off, 64);
    }
    if (lane == 0) {
        float rstd = rsqrtf(ss * (1.0f / HDIM) + EPS_F);
        int e0 = 0;
        for (int e = 1; e < NEXP; e++) if (acc[e] > acc[e0]) e0 = e;
        int e1 = (e0 == 0) ? 1 : 0;
        for (int e = 0; e < NEXP; e++)
            if (e != e0 && acc[e] > acc[e1]) e1 = e;
        float w0 = 1.0f / (1.0f + expf((acc[e1] - acc[e0]) * rstd));
        top_i[t * 2 + 0] = e0; top_i[t * 2 + 1] = e1;
        top_w[t * 2 + 0] = w0; top_w[t * 2 + 1] = 1.0f - w0;
        atomicAdd(&cnt[e0], 1);
        atomicAdd(&cnt[e1], 1);
    }
}

__global__ void k_prefix(const int* __restrict__ cnt, int* __restrict__ offs,
                         int* __restrict__ cur) {
    if (blockIdx.x == 0 && threadIdx.x == 0) {
        int a = 0;
        for (int e = 0; e < NEXP; e++) { offs[e] = a; cur[e] = a; a += cnt[e]; }
        offs[NEXP] = a;
    }
}

__global__ __launch_bounds__(256)
void k_fill(const int* __restrict__ top_i, int* __restrict__ cur,
            int* __restrict__ idxg, int* __restrict__ slot) {
    int t = blockIdx.x * blockDim.x + threadIdx.x;
    if (t >= S_LEN) return;
#pragma unroll
    for (int kk = 0; kk < 2; kk++) {
        int e = top_i[t * 2 + kk];
        int p = atomicAdd(&cur[e], 1);
        idxg[p] = t;
        slot[t * 2 + kk] = p;
    }
}

__global__ __launch_bounds__(256)
void k_gather(const u16* __restrict__ xnb, const int* __restrict__ idxg,
              u16* __restrict__ Xg) {
    int p = blockIdx.x;
    int t = idxg[p];
    const uint2* s = (const uint2*)(xnb + (size_t)t * HDIM);
    uint2* d = (uint2*)(Xg + (size_t)p * HDIM);
    d[threadIdx.x] = s[threadIdx.x];
}

__global__ __launch_bounds__(256)
void k_combine2(const float* __restrict__ OA, const float* __restrict__ OB,
                const int* __restrict__ slot, const float* __restrict__ top_w,
                float* __restrict__ out) {
    int t = blockIdx.x, tid = threadIdx.x;
    int s0 = slot[t * 2], s1 = slot[t * 2 + 1];
    float w0 = top_w[t * 2], w1 = top_w[t * 2 + 1];
    float4 a0 = ((const float4*)(OA + (size_t)s0 * HDIM))[tid];
    float4 b0 = ((const float4*)(OB + (size_t)s0 * HDIM))[tid];
    float4 a1 = ((const float4*)(OA + (size_t)s1 * HDIM))[tid];
    float4 b1 = ((const float4*)(OB + (size_t)s1 * HDIM))[tid];
    float4* o = (float4*)(out + (size_t)t * HDIM);
    float4 c = o[tid];
    c.x += w0 * (a0.x + b0.x) + w1 * (a1.x + b1.x);
    c.y += w0 * (a0.y + b0.y) + w1 * (a1.y + b1.y);
    c.z += w0 * (a0.z + b0.z) + w1 * (a1.z + b1.z);
    c.w += w0 * (a0.w + b0.w) + w1 * (a1.w + b1.w);
    o[tid] = c;
}

// ===========================================================================
extern "C" void kernel_launch(void* const* d_in, const int* in_sizes, int n_in,
                              void* d_out, int out_size, void* d_ws,
                              size_t ws_size, hipStream_t stream) {
    (void)in_sizes; (void)n_in; (void)out_size; (void)ws_size;
    const float* hidden = (const float*)d_in[0];
    const int*   pos    = (const int*)d_in[1];
    const float* wq     = (const float*)d_in[2];
    const float* wk     = (const float*)d_in[3];
    const float* wv     = (const float*)d_in[4];
    const float* wo     = (const float*)d_in[5];
    const float* innw   = (const float*)d_in[6];
    const float* postnw = (const float*)d_in[7];
    const float* gatew  = (const float*)d_in[8];
    const float* w1     = (const float*)d_in[9];
    const float* w3     = (const float*)d_in[10];
    const float* w2     = (const float*)d_in[11];
    float* out = (float*)d_out;

    // ---- workspace layout ----
    u16* w1t  = (u16*)d_ws;
    u16* w3t  = w1t + (size_t)NEXP * ISZ * HDIM;
    u16* w2t  = w3t + (size_t)NEXP * ISZ * HDIM;
    u16* qkvt = w2t + (size_t)NEXP * ISZ * HDIM;
    u16* wot  = qkvt + (size_t)1536 * HDIM;
    u16* xnb  = wot + (size_t)HDIM * HDIM;
    float* qbuf = (float*)(xnb + (size_t)S_LEN * HDIM);          // 2M fp32
    float* kbuf = qbuf + (size_t)S_LEN * HDIM;                   // 0.5M fp32
    u16* vb16   = (u16*)(kbuf + (size_t)S_LEN * NKVH * HD);      // 0.5M u16 (fp16)
    u16* qb2    = vb16 + (size_t)S_LEN * NKVH * HD;              // 2M u16 (fp16)
    u16* kb2    = qb2 + (size_t)S_LEN * HDIM;                    // 0.5M u16 (fp16)
    u16* attnb  = kb2 + (size_t)S_LEN * NKVH * HD;               // 2M u16 (bf16)
    float* oexpA = qbuf;  // overlay (16 MB): q/k/v/qb2/kb2 dead before w2
    u16* Xg  = attnb + (size_t)S_LEN * HDIM;
    u16* hg3 = Xg + (size_t)NSLOT * HDIM;                        // (unused now)
    u16* he  = hg3 + (size_t)NSLOT * ISZ;
    float* oexpB = (float*)(he + (size_t)NSLOT * ISZ);           // 16 MB
    int* ib  = (int*)(oexpB + (size_t)NSLOT * HDIM);
    int*   cnt   = ib;
    int*   offs  = ib + 16;
    int*   cur   = ib + 32;
    int*   top_i = ib + 64;
    int*   slot  = ib + 64 + 4096;
    int*   idxg  = ib + 64 + 8192;
    float* top_w = (float*)(ib + 64 + 12288);

    const long long HI = (long long)HDIM * ISZ;

    k_zero_ints<<<1, 64, 0, stream>>>(cnt, 64);
    k_rmsnorm_bf<<<S_LEN, 256, 0, stream>>>(hidden, innw, xnb);

    // weight transpose+convert (dst [N][K] bf16)
    k_cvt_t<<<dim3(16, 8, 1), 256, 0, stream>>>(wq, qkvt, 1024, 1024, 0, 0);
    k_cvt_t<<<dim3(4, 8, 1), 256, 0, stream>>>(wk, qkvt + (size_t)1024 * 1024, 1024, 256, 0, 0);
    k_cvt_t<<<dim3(4, 8, 1), 256, 0, stream>>>(wv, qkvt + (size_t)1280 * 1024, 1024, 256, 0, 0);
    k_cvt_t<<<dim3(16, 8, 1), 256, 0, stream>>>(wo, wot, 1024, 1024, 0, 0);
    k_cvt_t<<<dim3(56, 8, NEXP), 256, 0, stream>>>(w1, w1t, 1024, 3584, HI, HI);
    k_cvt_t<<<dim3(56, 8, NEXP), 256, 0, stream>>>(w3, w3t, 1024, 3584, HI, HI);
    k_cvt_t<<<dim3(16, 28, NEXP), 256, 0, stream>>>(w2, w2t, 3584, 1024, HI, HI);

    // qkv projection: q,k fp32 + v fp16
    k_gemm_bt<<<dim3(12, 16), 256, 0, stream>>>(xnb, qkvt, 2048, 1536, 1024, 3,
                                                qbuf, kbuf, nullptr, vb16);
    k_rope_cvt<<<(S_LEN * (NHEAD + NKVH) * 32) / 256, 256, 0, stream>>>(
        qbuf, kbuf, pos, qb2, kb2);
    k_attn_mfma<<<dim3(32, 16), 256, 0, stream>>>(qb2, kb2, vb16, attnb);
    // wo + residual -> d_out (h)
    k_gemm_bt<<<dim3(8, 16), 256, 0, stream>>>(attnb, wot, 2048, 1024, 1024, 2,
                                               out, nullptr, hidden, nullptr);
    // post-norm -> xnb ; gate from fp32 h (norm fused)
    k_rmsnorm_bf<<<S_LEN, 256, 0, stream>>>(out, postnw, xnb);
    k_gate<<<S_LEN, 64, 0, stream>>>(out, postnw, gatew, cnt, top_i, top_w);
    k_prefix<<<1, 1, 0, stream>>>(cnt, offs, cur);
    k_fill<<<S_LEN / 256, 256, 0, stream>>>(top_i, cur, idxg, slot);
    k_gather<<<NSLOT, 256, 0, stream>>>(xnb, idxg, Xg);

    // MoE: fused w1+w3 (silu(x@w1)*(x@w3) in one pass), then w2 split-K=2
    k_moe_w13<<<dim3(28 * 16 * NEXP), 256, 0, stream>>>(Xg, w1t, w3t, he, offs);
    k_moe_w2<<<dim3(8, 16, 16), 256, 0, stream>>>(he, w2t, oexpA, oexpB, offs);
    k_combine2<<<S_LEN, 256, 0, stream>>>(oexpA, oexpB, slot, top_w, out);
}

// Round 2
// 828.033 us; speedup vs baseline: 1.1110x; 1.0669x over previous
//
#include <hip/hip_runtime.h>
#include <math.h>

// ============================================================================
// MixtralDecoderLayer on MI355X — Round 6: occupancy + worklist for MoE GEMMs.
//
// Round-5 post-mortem: fused w13 was register-capped (dual 4x4 acc = 128 AGPR
// + 96 VGPR ~ 224/wave -> 2 waves/SIMD), occupancy 14.8%, MfmaUtil 20%,
// HBM 12% -> latency-bound with nothing to hide behind. Also 75% of launched
// MoE blocks early-exited (16 m-blocks vs ~4 working per expert) -> CU
// starvation.
//
// Changes:
//  * k_moe_w13: 512-thread block, same 128x128 fused tile, per-wave output
//    64x32 (acc 64 AGPR + ~60 VGPR ~ 124/wave, __launch_bounds__(512,4)) ->
//    4 waves/SIMD = 50% occupancy cap (2x round-5).
//  * Persistent worklist: k_prefix builds the exact (expert, m-block) item
//    list; k_moe_w13 / k_moe_w2 grid-stride over items. No empty blocks,
//    balanced tail.
// ============================================================================

typedef unsigned short u16;
typedef unsigned int u32;
typedef __attribute__((ext_vector_type(8))) short s16x8;
typedef __attribute__((ext_vector_type(8))) _Float16 f16x8;
typedef __attribute__((ext_vector_type(4))) float f32x4;

#define S_LEN 2048
#define HDIM  1024
#define NHEAD 16
#define NKVH  4
#define HD    64
#define ISZ   3584
#define NEXP  8
#define NSLOT 4096
#define EPS_F 1e-5f
#define NEG_INF -1e30f
#define LOG2E 1.44269504f

__device__ __forceinline__ float bf2f(u16 u) {
    union { u32 i; float f; } c; c.i = ((u32)u) << 16; return c.f;
}
__device__ __forceinline__ u16 f2bf(float f) {
    union { float f; u32 i; } c; c.f = f;
    u32 r = (c.i + 0x7fffu + ((c.i >> 16) & 1u)) >> 16;
    return (u16)r;
}
__device__ __forceinline__ u16 f2h_bits(float f) {
    union { _Float16 h; u16 u; } c; c.h = (_Float16)f; return c.u;
}
__device__ __forceinline__ void async16(const u16* g, u16* l) {
    __builtin_amdgcn_global_load_lds(
        (const __attribute__((address_space(1))) void*)g,
        (__attribute__((address_space(3))) void*)l, 16, 0, 0);
}

// ---------------------------------------------------------------------------
__global__ void k_zero_ints(int* __restrict__ p, int n) {
    int i = blockIdx.x * blockDim.x + threadIdx.x;
    if (i < n) p[i] = 0;
}

// ---------------------------------------------------------------------------
__global__ __launch_bounds__(256)
void k_rmsnorm_bf(const float* __restrict__ x, const float* __restrict__ w,
                  u16* __restrict__ out) {
    int t = blockIdx.x;
    int tid = threadIdx.x;
    float4 v = ((const float4*)(x + (size_t)t * HDIM))[tid];
    float ss = v.x * v.x + v.y * v.y + v.z * v.z + v.w * v.w;
#pragma unroll
    for (int off = 32; off >= 1; off >>= 1) ss += __shfl_xor(ss, off, 64);
    __shared__ float red[4];
    if ((tid & 63) == 0) red[tid >> 6] = ss;
    __syncthreads();
    float tot = red[0] + red[1] + red[2] + red[3];
    float rstd = rsqrtf(tot * (1.0f / HDIM) + EPS_F);
    float4 wv = ((const float4*)w)[tid];
    uint2 pk;
    pk.x = (u32)f2bf(v.x * rstd * wv.x) | ((u32)f2bf(v.y * rstd * wv.y) << 16);
    pk.y = (u32)f2bf(v.z * rstd * wv.z) | ((u32)f2bf(v.w * rstd * wv.w) << 16);
    ((uint2*)(out + (size_t)t * HDIM))[tid] = pk;
}

// ---------------------------------------------------------------------------
// Transpose + convert: src fp32 [R][C] -> dst bf16 [C][R].
__global__ __launch_bounds__(256)
void k_cvt_t(const float* __restrict__ src, u16* __restrict__ dst,
             int R, int C, long long srcZ, long long dstZ) {
    const int z = blockIdx.z;
    src += (size_t)z * srcZ;
    dst += (size_t)z * dstZ;
    const int lane = threadIdx.x & 63, w = threadIdx.x >> 6;
    const int c = blockIdx.x * 64 + lane;
    const int r0 = blockIdx.y * 128 + w * 32;
    float v[32];
#pragma unroll
    for (int i = 0; i < 32; i++) v[i] = src[(size_t)(r0 + i) * C + c];
#pragma unroll
    for (int g = 0; g < 4; g++) {
        uint4 pk;
        pk.x = (u32)f2bf(v[g * 8 + 0]) | ((u32)f2bf(v[g * 8 + 1]) << 16);
        pk.y = (u32)f2bf(v[g * 8 + 2]) | ((u32)f2bf(v[g * 8 + 3]) << 16);
        pk.z = (u32)f2bf(v[g * 8 + 4]) | ((u32)f2bf(v[g * 8 + 5]) << 16);
        pk.w = (u32)f2bf(v[g * 8 + 6]) | ((u32)f2bf(v[g * 8 + 7]) << 16);
        *(uint4*)(&dst[(size_t)c * R + r0 + g * 8]) = pk;
    }
}

// ---------------------------------------------------------------------------
// Stage one 128x32 A-tile + 128x32 B-tile (bf16) into `buf` via async16.
__device__ __forceinline__ void stage32(const u16* __restrict__ A,
                                        const u16* __restrict__ Bt, int K,
                                        int rowA0, int rowAmax, int n0, int kc,
                                        u16* buf, int wid, int sr, int sc) {
#pragma unroll
    for (int t = 0; t < 2; t++) {
        int row = wid * 32 + t * 16 + sr;
        int ck = (sc ^ (row & 3)) << 3;
        int ra = rowA0 + row;
        if (ra > rowAmax) ra = rowAmax;
        u16* ldsA = buf + (wid * 32 + t * 16) * 32;
        async16(A + (size_t)ra * K + kc + ck, ldsA);
        async16(Bt + (size_t)(n0 + row) * K + kc + ck, ldsA + 4096);
    }
}

// 512-thread fused staging: A + B1 + B3 128x32 tiles (buffer 12288 elems).
__device__ __forceinline__ void stage_w13(const u16* __restrict__ A,
                                          const u16* __restrict__ B1,
                                          const u16* __restrict__ B3,
                                          int rowA0, int n0, int kc,
                                          u16* buf, int wid, int sr, int sc) {
    int row = wid * 16 + sr;              // 0..127, one row per (wave,lane/4)
    int ck = (sc ^ (row & 3)) << 3;
    int ra = rowA0 + row;
    if (ra > NSLOT - 1) ra = NSLOT - 1;
    u16* dst = buf + (wid * 16) * 32;     // wave-uniform LDS base
    async16(A  + (size_t)ra * HDIM + kc + ck, dst);
    async16(B1 + (size_t)(n0 + row) * HDIM + kc + ck, dst + 4096);
    async16(B3 + (size_t)(n0 + row) * HDIM + kc + ck, dst + 8192);
}

// ---------------------------------------------------------------------------
// Double-buffered MFMA GEMM core: C[128,128] += A[rows,kbeg:kend] @ Bt^T.
// lds must be 16384 u16 (32 KB): two 8192-elem buffers (A @0, B @4096 each).
__device__ __forceinline__ void gemm128_dbuf(
    const u16* __restrict__ A, const u16* __restrict__ Bt, int K,
    int kbeg, int kend, int rowA0, int rowAmax, int n0,
    u16* lds, f32x4 acc[4][4]) {
    const int tid = threadIdx.x;
    const int lane = tid & 63, wid = tid >> 6;
    const int sr = lane >> 2, sc = lane & 3;
    const int ln = lane & 15, q = lane >> 4;
    const int wm = wid >> 1, wn = wid & 1;
    stage32(A, Bt, K, rowA0, rowAmax, n0, kbeg, lds, wid, sr, sc);
    int pp = 0;
    for (int kc = kbeg; kc < kend; kc += 32) {
        u16* cur = lds + pp * 8192;
        u16* nxt = lds + (pp ^ 1) * 8192;
        pp ^= 1;
        __syncthreads();   // drains vmcnt -> stage(kc) done; stage was issued
                           // one compute-phase ago, so latency is overlapped
        if (kc + 32 < kend)
            stage32(A, Bt, K, rowA0, rowAmax, n0, kc + 32, nxt, wid, sr, sc);
        s16x8 af[4], bfv[4];
#pragma unroll
        for (int i = 0; i < 4; i++) {
            int ar = wm * 64 + i * 16 + ln;
            af[i] = *(const s16x8*)(cur + ar * 32 + ((q ^ (ar & 3)) << 3));
            int br = wn * 64 + i * 16 + ln;
            bfv[i] = *(const s16x8*)(cur + 4096 + br * 32 + ((q ^ (br & 3)) << 3));
        }
#pragma unroll
        for (int i = 0; i < 4; i++)
#pragma unroll
            for (int j = 0; j < 4; j++)
                acc[i][j] = __builtin_amdgcn_mfma_f32_16x16x32_bf16(
                    af[i], bfv[j], acc[i][j], 0, 0, 0);
    }
}

// ---------------------------------------------------------------------------
// Flat GEMM.  mode 0: fp32->F0 | 1: bf16->O16 | 2: fp32+RES->F0 |
//             3: qkv split -> F0(q fp32) F1(k fp32) O16(v fp16 bits)
__global__ __launch_bounds__(256, 2)
void k_gemm_bt(const u16* __restrict__ A, const u16* __restrict__ Bt,
               int M, int N, int K, int mode,
               float* __restrict__ F0, float* __restrict__ F1,
               const float* __restrict__ RES, u16* __restrict__ O16) {
    __shared__ u16 lds[16384];
    const int m0 = blockIdx.y * 128, n0 = blockIdx.x * 128;
    f32x4 acc[4][4];
#pragma unroll
    for (int i = 0; i < 4; i++)
#pragma unroll
        for (int j = 0; j < 4; j++) acc[i][j] = (f32x4){0.f, 0.f, 0.f, 0.f};
    gemm128_dbuf(A, Bt, K, 0, K, m0, M - 1, n0, lds, acc);
    const int lane = threadIdx.x & 63, wid = threadIdx.x >> 6;
    const int ln = lane & 15, q = lane >> 4, wm = wid >> 1, wn = wid & 1;
#pragma unroll
    for (int i = 0; i < 4; i++) {
#pragma unroll
        for (int r = 0; r < 4; r++) {
            int m = m0 + wm * 64 + i * 16 + q * 4 + r;
#pragma unroll
            for (int j = 0; j < 4; j++) {
                int n = n0 + wn * 64 + j * 16 + ln;
                float v = acc[i][j][r];
                if (mode == 0) {
                    F0[(size_t)m * N + n] = v;
                } else if (mode == 1) {
                    O16[(size_t)m * N + n] = f2bf(v);
                } else if (mode == 2) {
                    F0[(size_t)m * N + n] = v + RES[(size_t)m * N + n];
                } else {
                    if (n < 1024)       F0[(size_t)m * 1024 + n] = v;
                    else if (n < 1280)  F1[(size_t)m * 256 + (n - 1024)] = v;
                    else                O16[(size_t)m * 256 + (n - 1280)] = f2h_bits(v);
                }
            }
        }
    }
}

// ---------------------------------------------------------------------------
// Fused grouped MoE GEMM: He = silu(Xg @ w1^T) * (Xg @ w3^T), per expert.
// 512 threads / 8 waves per block, 128x128 tile of BOTH products.
// Per-wave output 64x32 per product: acc = 64 AGPR + ~60 VGPR -> 4 waves/SIMD.
// Persistent: grid-strides over worklist items (mi = (expert, m-block)) x 28
// n-blocks. No empty blocks.
__global__ __launch_bounds__(512, 4)
void k_moe_w13(const u16* __restrict__ Xg, const u16* __restrict__ W1T,
               const u16* __restrict__ W3T, u16* __restrict__ He,
               const int* __restrict__ offs, const int* __restrict__ mlist,
               const int* __restrict__ nitems) {
    __shared__ u16 lds[24576];            // 2 x (A 4096 + B1 4096 + B3 4096)
    const int NB = ISZ / 128;             // 28 n-blocks
    const int tot = nitems[0] * NB;
    const int tid = threadIdx.x;
    const int lane = tid & 63, wid = tid >> 6;
    const int sr = lane >> 2, sc = lane & 3;
    const int ln = lane & 15, q = lane >> 4;
    const int wm = wid >> 2, wn = wid & 3;  // 2 x 4 wave grid
    for (int it = blockIdx.x; it < tot; it += gridDim.x) {
        const int mi = it / NB, nb = it - mi * NB;
        const int em = mlist[mi];
        const int e = em >> 8, mb = em & 255;
        const int base = offs[e], cnt = offs[e + 1] - base;
        const int m0 = mb * 128, n0 = nb * 128;
        const int rowA0 = base + m0;
        const u16* B1 = W1T + (size_t)e * ISZ * HDIM;
        const u16* B3 = W3T + (size_t)e * ISZ * HDIM;
        f32x4 acc1[4][2], acc3[4][2];
#pragma unroll
        for (int i = 0; i < 4; i++)
#pragma unroll
            for (int j = 0; j < 2; j++) {
                acc1[i][j] = (f32x4){0.f, 0.f, 0.f, 0.f};
                acc3[i][j] = (f32x4){0.f, 0.f, 0.f, 0.f};
            }
        __syncthreads();  // all waves done reading LDS of the previous item
        stage_w13(Xg, B1, B3, rowA0, n0, 0, lds, wid, sr, sc);
        int pp = 0;
        for (int kc = 0; kc < HDIM; kc += 32) {
            u16* cur = lds + pp * 12288;
            u16* nxt = lds + (pp ^ 1) * 12288;
            pp ^= 1;
            __syncthreads();
            if (kc + 32 < HDIM)
                stage_w13(Xg, B1, B3, rowA0, n0, kc + 32, nxt, wid, sr, sc);
            s16x8 af[4], b1f[2], b3f[2];
#pragma unroll
            for (int i = 0; i < 4; i++) {
                int ar = wm * 64 + i * 16 + ln;
                af[i] = *(const s16x8*)(cur + ar * 32 + ((q ^ (ar & 3)) << 3));
            }
#pragma unroll
            for (int j = 0; j < 2; j++) {
                int br = wn * 32 + j * 16 + ln;
                int bo = br * 32 + ((q ^ (br & 3)) << 3);
                b1f[j] = *(const s16x8*)(cur + 4096 + bo);
                b3f[j] = *(const s16x8*)(cur + 8192 + bo);
            }
#pragma unroll
            for (int i = 0; i < 4; i++)
#pragma unroll
                for (int j = 0; j < 2; j++) {
                    acc1[i][j] = __builtin_amdgcn_mfma_f32_16x16x32_bf16(
                        af[i], b1f[j], acc1[i][j], 0, 0, 0);
                    acc3[i][j] = __builtin_amdgcn_mfma_f32_16x16x32_bf16(
                        af[i], b3f[j], acc3[i][j], 0, 0, 0);
                }
        }
        // epilogue: silu(acc1) * acc3 -> He (bf16)
#pragma unroll
        for (int i = 0; i < 4; i++) {
#pragma unroll
            for (int r = 0; r < 4; r++) {
                int mloc = wm * 64 + i * 16 + q * 4 + r;
                if (m0 + mloc >= cnt) continue;
                size_t row = (size_t)(base + m0 + mloc);
#pragma unroll
                for (int j = 0; j < 2; j++) {
                    int n = n0 + wn * 32 + j * 16 + ln;
                    float v1 = acc1[i][j][r];
                    float v3 = acc3[i][j][r];
                    float s = v1 / (1.0f + expf(-v1));
                    He[row * ISZ + n] = f2bf(s * v3);
                }
            }
        }
    }
}

// ---------------------------------------------------------------------------
// MoE w2 GEMM, split-K=2, persistent worklist: item = mi*16 + (half*8 + nb).
__global__ __launch_bounds__(256, 3)
void k_moe_w2(const u16* __restrict__ He, const u16* __restrict__ W2T,
              float* __restrict__ OA, float* __restrict__ OB,
              const int* __restrict__ offs, const int* __restrict__ mlist,
              const int* __restrict__ nitems) {
    __shared__ u16 lds[16384];
    const int tot = nitems[0] * 16;
    const int lane = threadIdx.x & 63, wid = threadIdx.x >> 6;
    const int ln = lane & 15, q = lane >> 4, wm = wid >> 1, wn = wid & 1;
    for (int it = blockIdx.x; it < tot; it += gridDim.x) {
        const int mi = it >> 4, rr = it & 15;
        const int nb = rr & 7, half = rr >> 3;
        const int em = mlist[mi];
        const int e = em >> 8, mb = em & 255;
        const int base = offs[e], cnt = offs[e + 1] - base;
        const int m0 = mb * 128, n0 = nb * 128;
        const u16* Bt = W2T + (size_t)e * HDIM * ISZ;
        f32x4 acc[4][4];
#pragma unroll
        for (int i = 0; i < 4; i++)
#pragma unroll
            for (int j = 0; j < 4; j++) acc[i][j] = (f32x4){0.f, 0.f, 0.f, 0.f};
        __syncthreads();  // protect LDS from previous item's readers
        gemm128_dbuf(He, Bt, ISZ, half * (ISZ / 2), (half + 1) * (ISZ / 2),
                     base + m0, NSLOT - 1, n0, lds, acc);
        float* F0 = half ? OB : OA;
#pragma unroll
        for (int i = 0; i < 4; i++) {
#pragma unroll
            for (int r = 0; r < 4; r++) {
                int mloc = wm * 64 + i * 16 + q * 4 + r;
                if (m0 + mloc >= cnt) continue;
                size_t row = (size_t)(base + m0 + mloc);
#pragma unroll
                for (int j = 0; j < 4; j++) {
                    int n = n0 + wn * 64 + j * 16 + ln;
                    F0[row * HDIM + n] = acc[i][j][r];
                }
            }
        }
    }
}

// ---------------------------------------------------------------------------
// RoPE + convert to fp16 bits.
__global__ __launch_bounds__(256)
void k_rope_cvt(const float* __restrict__ q, const float* __restrict__ k,
                const int* __restrict__ pos, u16* __restrict__ qb2,
                u16* __restrict__ kb2) {
    int id = blockIdx.x * blockDim.x + threadIdx.x;
    int d = id & 31;
    int hh = (id >> 5) % (NHEAD + NKVH);
    int s = id / ((NHEAD + NKVH) * 32);
    float p = (float)pos[s];
    float inv = exp2f(-((float)(2 * d) / (float)HD) * log2f(1.0e6f));
    float ang = p * inv;
    float c = cosf(ang), sn = sinf(ang);
    const float* sp; u16* dp;
    if (hh < NHEAD) {
        sp = q + (size_t)s * (NHEAD * HD) + hh * HD;
        dp = qb2 + (size_t)s * (NHEAD * HD) + hh * HD;
    } else {
        sp = k + (size_t)s * (NKVH * HD) + (hh - NHEAD) * HD;
        dp = kb2 + (size_t)s * (NKVH * HD) + (hh - NHEAD) * HD;
    }
    float x1 = sp[d], x2 = sp[d + 32];
    dp[d]      = f2h_bits(x1 * c - x2 * sn);
    dp[d + 32] = f2h_bits(x2 * c + x1 * sn);
}

// ---------------------------------------------------------------------------
// MFMA flash attention (fp16 inputs, fp32 accumulate). Round-3-verified.
__global__ __launch_bounds__(256)
void k_attn_mfma(const u16* __restrict__ qb, const u16* __restrict__ kb,
                 const u16* __restrict__ vb, u16* __restrict__ ob) {
    __shared__ u16 Qs[64 * 64];
    __shared__ u16 Ks[64 * 64];
    __shared__ u16 Vt[64 * 64];
    __shared__ u16 Ps[64 * 64];
    const int qt = blockIdx.x, h = blockIdx.y, kvh = h >> 2;
    const int tid = threadIdx.x, lane = tid & 63, w = tid >> 6;
    const int ln = lane & 15, quad = lane >> 4;

#pragma unroll
    for (int p = 0; p < 2; p++) {
        int r = p * 32 + (tid >> 3), c = tid & 7;
        uint4 v = *(const uint4*)(qb + (size_t)(qt * 64 + r) * (NHEAD * HD) +
                                  h * HD + c * 8);
        *(uint4*)&Qs[r * 64 + ((c ^ (r & 7)) << 3)] = v;
    }

    float m_[4], l_[4];
    f32x4 Oa[4];
#pragma unroll
    for (int r = 0; r < 4; r++) { m_[r] = NEG_INF; l_[r] = 0.0f; }
#pragma unroll
    for (int nt = 0; nt < 4; nt++) Oa[nt] = (f32x4){0.f, 0.f, 0.f, 0.f};

    for (int kt = 0; kt <= qt; kt++) {
        __syncthreads();
#pragma unroll
        for (int p = 0; p < 2; p++) {
            int r = p * 32 + (tid >> 3), c = tid & 7;
            uint4 v = *(const uint4*)(kb + (size_t)(kt * 64 + r) * (NKVH * HD) +
                                      kvh * HD + c * 8);
            *(uint4*)&Ks[r * 64 + ((c ^ (r & 7)) << 3)] = v;
        }
        {
            int s = tid & 63;
#pragma unroll
            for (int half = 0; half < 2; half++) {
                int d0 = w * 16 + half * 8;
                uint4 v = *(const uint4*)(vb + (size_t)(kt * 64 + s) * (NKVH * HD) +
                                          kvh * HD + d0);
                u16 a[8];
                a[0] = (u16)(v.x & 0xffff); a[1] = (u16)(v.x >> 16);
                a[2] = (u16)(v.y & 0xffff); a[3] = (u16)(v.y >> 16);
                a[4] = (u16)(v.z & 0xffff); a[5] = (u16)(v.z >> 16);
                a[6] = (u16)(v.w & 0xffff); a[7] = (u16)(v.w >> 16);
#pragma unroll
                for (int j = 0; j < 8; j++) {
                    int d = d0 + j;
                    Vt[d * 64 + (((s >> 3) ^ (d & 7)) << 3) + (s & 7)] = a[j];
                }
            }
        }
        __syncthreads();

        f32x4 sc[4];
#pragma unroll
        for (int nt = 0; nt < 4; nt++) sc[nt] = (f32x4){0.f, 0.f, 0.f, 0.f};
#pragma unroll
        for (int ks = 0; ks < 2; ks++) {
            int arow = 16 * w + ln;
            f16x8 af = *(const f16x8*)&Qs[arow * 64 +
                                          (((ks * 4 + quad) ^ (arow & 7)) << 3)];
#pragma unroll
            for (int nt = 0; nt < 4; nt++) {
                int brow = nt * 16 + ln;
                f16x8 bf = *(const f16x8*)&Ks[brow * 64 +
                                              (((ks * 4 + quad) ^ (brow & 7)) << 3)];
                sc[nt] = __builtin_amdgcn_mfma_f32_16x16x32_f16(af, bf, sc[nt],
                                                                0, 0, 0);
            }
        }

        const bool diag = (kt == qt);
        float mt[4];
#pragma unroll
        for (int r = 0; r < 4; r++) {
            int qrow = quad * 4 + r + 16 * w;
#pragma unroll
            for (int nt = 0; nt < 4; nt++) {
                float s = sc[nt][r] * 0.125f;
                if (diag && (nt * 16 + ln) > qrow) s = NEG_INF;
                sc[nt][r] = s;
            }
            mt[r] = fmaxf(fmaxf(sc[0][r], sc[1][r]), fmaxf(sc[2][r], sc[3][r]));
        }
#pragma unroll
        for (int off = 8; off >= 1; off >>= 1)
#pragma unroll
            for (int r = 0; r < 4; r++)
                mt[r] = fmaxf(mt[r], __shfl_xor(mt[r], off, 64));

        float rs[4];
#pragma unroll
        for (int r = 0; r < 4; r++) {
            float mn = fmaxf(m_[r], mt[r]);
            float al = exp2f((m_[r] - mn) * LOG2E);
            m_[r] = mn;
            float acc0 = 0.0f;
#pragma unroll
            for (int nt = 0; nt < 4; nt++) {
                float pv = exp2f((sc[nt][r] - mn) * LOG2E);
                sc[nt][r] = pv;
                acc0 += pv;
            }
            rs[r] = acc0;
            l_[r] *= al;
#pragma unroll
            for (int nt = 0; nt < 4; nt++) Oa[nt][r] *= al;
        }
#pragma unroll
        for (int off = 8; off >= 1; off >>= 1)
#pragma unroll
            for (int r = 0; r < 4; r++) rs[r] += __shfl_xor(rs[r], off, 64);
#pragma unroll
        for (int r = 0; r < 4; r++) l_[r] += rs[r];

#pragma unroll
        for (int r = 0; r < 4; r++) {
            int row = 16 * w + quad * 4 + r;
#pragma unroll
            for (int nt = 0; nt < 4; nt++) {
                int ch = nt * 2 + (ln >> 3);
                Ps[row * 64 + ((ch ^ (row & 7)) << 3) + (ln & 7)] =
                    f2h_bits(sc[nt][r]);
            }
        }
        __syncthreads();

#pragma unroll
        for (int ks = 0; ks < 2; ks++) {
            int arow = 16 * w + ln;
            f16x8 pf = *(const f16x8*)&Ps[arow * 64 +
                                          (((ks * 4 + quad) ^ (arow & 7)) << 3)];
#pragma unroll
            for (int nt = 0; nt < 4; nt++) {
                int vrow = nt * 16 + ln;
                f16x8 vf = *(const f16x8*)&Vt[vrow * 64 +
                                              (((ks * 4 + quad) ^ (vrow & 7)) << 3)];
                Oa[nt] = __builtin_amdgcn_mfma_f32_16x16x32_f16(pf, vf, Oa[nt],
                                                                0, 0, 0);
            }
        }
    }

#pragma unroll
    for (int r = 0; r < 4; r++) {
        float inv = 1.0f / l_[r];
        int sg = qt * 64 + 16 * w + quad * 4 + r;
#pragma unroll
        for (int nt = 0; nt < 4; nt++) {
            int d = nt * 16 + ln;
            ob[(size_t)sg * HDIM + h * HD + d] = f2bf(Oa[nt][r] * inv);
        }
    }
}

// ---------------------------------------------------------------------------
__global__ __launch_bounds__(64)
void k_gate(const float* __restrict__ Hst, const float* __restrict__ PW,
            const float* __restrict__ GW, int* __restrict__ cnt,
            int* __restrict__ top_i, float* __restrict__ top_w) {
    int t = blockIdx.x;
    int lane = threadIdx.x;
    const float* hrow = Hst + (size_t)t * HDIM;
    float ss = 0.0f;
    float acc[NEXP] = {};
    for (int hh = lane; hh < HDIM; hh += 64) {
        float hv = hrow[hh];
        ss += hv * hv;
        float xw = hv * PW[hh];
        const float* g = GW + (size_t)hh * NEXP;
#pragma unroll
        for (int e = 0; e < NEXP; e++) acc[e] += xw * g[e];
    }
#pragma unroll
    for (int off = 32; off >= 1; off >>= 1) {
        ss += __shfl_xor(ss, off, 64);
#pragma unroll
        for (int e = 0; e < NEXP; e++) acc[e] += __shfl_xor(acc[e], off, 64);
    }
    if (lane == 0) {
        float rstd = rsqrtf(ss * (1.0f / HDIM) + EPS_F);
        int e0 = 0;
        for (int e = 1; e < NEXP; e++) if (acc[e] > acc[e0]) e0 = e;
        int e1 = (e0 == 0) ? 1 : 0;
        for (int e = 0; e < NEXP; e++)
            if (e != e0 && acc[e] > acc[e1]) e1 = e;
        float w0 = 1.0f / (1.0f + expf((acc[e1] - acc[e0]) * rstd));
        top_i[t * 2 + 0] = e0; top_i[t * 2 + 1] = e1;
        top_w[t * 2 + 0] = w0; top_w[t * 2 + 1] = 1.0f - w0;
        atomicAdd(&cnt[e0], 1);
        atomicAdd(&cnt[e1], 1);
    }
}

// prefix sums + worklist of (expert, m-block) items for the MoE GEMMs.
__global__ void k_prefix(const int* __restrict__ cnt, int* __restrict__ offs,
                         int* __restrict__ cur, int* __restrict__ mlist,
                         int* __restrict__ nitems) {
    if (blockIdx.x == 0 && threadIdx.x == 0) {
        int a = 0, idx = 0;
        for (int e = 0; e < NEXP; e++) {
            offs[e] = a; cur[e] = a;
            int c = cnt[e];
            int nmb = (c + 127) >> 7;
            for (int mb = 0; mb < nmb; mb++) mlist[idx++] = (e << 8) | mb;
            a += c;
        }
        offs[NEXP] = a;
        nitems[0] = idx;
    }
}

__global__ __launch_bounds__(256)
void k_fill(const int* __restrict__ top_i, int* __restrict__ cur,
            int* __restrict__ idxg, int* __restrict__ slot) {
    int t = blockIdx.x * blockDim.x + threadIdx.x;
    if (t >= S_LEN) return;
#pragma unroll
    for (int kk = 0; kk < 2; kk++) {
        int e = top_i[t * 2 + kk];
        int p = atomicAdd(&cur[e], 1);
        idxg[p] = t;
        slot[t * 2 + kk] = p;
    }
}

__global__ __launch_bounds__(256)
void k_gather(const u16* __restrict__ xnb, const int* __restrict__ idxg,
              u16* __restrict__ Xg) {
    int p = blockIdx.x;
    int t = idxg[p];
    const uint2* s = (const uint2*)(xnb + (size_t)t * HDIM);
    uint2* d = (uint2*)(Xg + (size_t)p * HDIM);
    d[threadIdx.x] = s[threadIdx.x];
}

__global__ __launch_bounds__(256)
void k_combine2(const float* __restrict__ OA, const float* __restrict__ OB,
                const int* __restrict__ slot, const float* __restrict__ top_w,
                float* __restrict__ out) {
    int t = blockIdx.x, tid = threadIdx.x;
    int s0 = slot[t * 2], s1 = slot[t * 2 + 1];
    float w0 = top_w[t * 2], w1 = top_w[t * 2 + 1];
    float4 a0 = ((const float4*)(OA + (size_t)s0 * HDIM))[tid];
    float4 b0 = ((const float4*)(OB + (size_t)s0 * HDIM))[tid];
    float4 a1 = ((const float4*)(OA + (size_t)s1 * HDIM))[tid];
    float4 b1 = ((const float4*)(OB + (size_t)s1 * HDIM))[tid];
    float4* o = (float4*)(out + (size_t)t * HDIM);
    float4 c = o[tid];
    c.x += w0 * (a0.x + b0.x) + w1 * (a1.x + b1.x);
    c.y += w0 * (a0.y + b0.y) + w1 * (a1.y + b1.y);
    c.z += w0 * (a0.z + b0.z) + w1 * (a1.z + b1.z);
    c.w += w0 * (a0.w + b0.w) + w1 * (a1.w + b1.w);
    o[tid] = c;
}

// ===========================================================================
extern "C" void kernel_launch(void* const* d_in, const int* in_sizes, int n_in,
                              void* d_out, int out_size, void* d_ws,
                              size_t ws_size, hipStream_t stream) {
    (void)in_sizes; (void)n_in; (void)out_size; (void)ws_size;
    const float* hidden = (const float*)d_in[0];
    const int*   pos    = (const int*)d_in[1];
    const float* wq     = (const float*)d_in[2];
    const float* wk     = (const float*)d_in[3];
    const float* wv     = (const float*)d_in[4];
    const float* wo     = (const float*)d_in[5];
    const float* innw   = (const float*)d_in[6];
    const float* postnw = (const float*)d_in[7];
    const float* gatew  = (const float*)d_in[8];
    const float* w1     = (const float*)d_in[9];
    const float* w3     = (const float*)d_in[10];
    const float* w2     = (const float*)d_in[11];
    float* out = (float*)d_out;

    // ---- workspace layout ----
    u16* w1t  = (u16*)d_ws;
    u16* w3t  = w1t + (size_t)NEXP * ISZ * HDIM;
    u16* w2t  = w3t + (size_t)NEXP * ISZ * HDIM;
    u16* qkvt = w2t + (size_t)NEXP * ISZ * HDIM;
    u16* wot  = qkvt + (size_t)1536 * HDIM;
    u16* xnb  = wot + (size_t)HDIM * HDIM;
    float* qbuf = (float*)(xnb + (size_t)S_LEN * HDIM);          // 2M fp32
    float* kbuf = qbuf + (size_t)S_LEN * HDIM;                   // 0.5M fp32
    u16* vb16   = (u16*)(kbuf + (size_t)S_LEN * NKVH * HD);      // 0.5M u16 (fp16)
    u16* qb2    = vb16 + (size_t)S_LEN * NKVH * HD;              // 2M u16 (fp16)
    u16* kb2    = qb2 + (size_t)S_LEN * HDIM;                    // 0.5M u16 (fp16)
    u16* attnb  = kb2 + (size_t)S_LEN * NKVH * HD;               // 2M u16 (bf16)
    float* oexpA = qbuf;  // overlay (16 MB): q/k/v/qb2/kb2 dead before w2
    u16* Xg  = attnb + (size_t)S_LEN * HDIM;
    u16* hg3 = Xg + (size_t)NSLOT * HDIM;                        // (unused now)
    u16* he  = hg3 + (size_t)NSLOT * ISZ;
    float* oexpB = (float*)(he + (size_t)NSLOT * ISZ);           // 16 MB
    int* ib  = (int*)(oexpB + (size_t)NSLOT * HDIM);
    int*   cnt   = ib;
    int*   offs  = ib + 16;
    int*   cur   = ib + 32;
    int*   top_i = ib + 64;
    int*   slot  = ib + 64 + 4096;
    int*   idxg  = ib + 64 + 8192;
    float* top_w = (float*)(ib + 64 + 12288);
    int*   mlist = ib + 64 + 16384;           // up to 128 items
    int*   nitems = ib + 64 + 16384 + 128;

    const long long HI = (long long)HDIM * ISZ;

    k_zero_ints<<<1, 64, 0, stream>>>(cnt, 64);
    k_rmsnorm_bf<<<S_LEN, 256, 0, stream>>>(hidden, innw, xnb);

    // weight transpose+convert (dst [N][K] bf16)
    k_cvt_t<<<dim3(16, 8, 1), 256, 0, stream>>>(wq, qkvt, 1024, 1024, 0, 0);
    k_cvt_t<<<dim3(4, 8, 1), 256, 0, stream>>>(wk, qkvt + (size_t)1024 * 1024, 1024, 256, 0, 0);
    k_cvt_t<<<dim3(4, 8, 1), 256, 0, stream>>>(wv, qkvt + (size_t)1280 * 1024, 1024, 256, 0, 0);
    k_cvt_t<<<dim3(16, 8, 1), 256, 0, stream>>>(wo, wot, 1024, 1024, 0, 0);
    k_cvt_t<<<dim3(56, 8, NEXP), 256, 0, stream>>>(w1, w1t, 1024, 3584, HI, HI);
    k_cvt_t<<<dim3(56, 8, NEXP), 256, 0, stream>>>(w3, w3t, 1024, 3584, HI, HI);
    k_cvt_t<<<dim3(16, 28, NEXP), 256, 0, stream>>>(w2, w2t, 3584, 1024, HI, HI);

    // qkv projection: q,k fp32 + v fp16
    k_gemm_bt<<<dim3(12, 16), 256, 0, stream>>>(xnb, qkvt, 2048, 1536, 1024, 3,
                                                qbuf, kbuf, nullptr, vb16);
    k_rope_cvt<<<(S_LEN * (NHEAD + NKVH) * 32) / 256, 256, 0, stream>>>(
        qbuf, kbuf, pos, qb2, kb2);
    k_attn_mfma<<<dim3(32, 16), 256, 0, stream>>>(qb2, kb2, vb16, attnb);
    // wo + residual -> d_out (h)
    k_gemm_bt<<<dim3(8, 16), 256, 0, stream>>>(attnb, wot, 2048, 1024, 1024, 2,
                                               out, nullptr, hidden, nullptr);
    // post-norm -> xnb ; gate from fp32 h (norm fused)
    k_rmsnorm_bf<<<S_LEN, 256, 0, stream>>>(out, postnw, xnb);
    k_gate<<<S_LEN, 64, 0, stream>>>(out, postnw, gatew, cnt, top_i, top_w);
    k_prefix<<<1, 1, 0, stream>>>(cnt, offs, cur, mlist, nitems);
    k_fill<<<S_LEN / 256, 256, 0, stream>>>(top_i, cur, idxg, slot);
    k_gather<<<NSLOT, 256, 0, stream>>>(xnb, idxg, Xg);

    // MoE: fused w1+w3 persistent (silu(x@w1)*(x@w3)), then w2 split-K=2
    k_moe_w13<<<dim3(512), 512, 0, stream>>>(Xg, w1t, w3t, he, offs, mlist,
                                             nitems);
    k_moe_w2<<<dim3(1024), 256, 0, stream>>>(he, w2t, oexpA, oexpB, offs,
                                             mlist, nitems);
    k_combine2<<<S_LEN, 256, 0, stream>>>(oexpA, oexpB, slot, top_w, out);
}

// Round 3
// 824.492 us; speedup vs baseline: 1.1158x; 1.0043x over previous
//
#include <hip/hip_runtime.h>
#include <math.h>

// ============================================================================
// MixtralDecoderLayer on MI355X — Round 7: counted-vmcnt 3-buffer pipeline.
//
// Round-6 post-mortem: occupancy fix worked (15->36%, MfmaUtil 20->29%) but
// the GEMMs are still stall-bound at the per-k-step barrier: __syncthreads
// drains vmcnt(0) against a stage issued one ~300cy compute phase earlier,
// vs ~500-900cy LLC/HBM latency -> ~700cy stall per k-step.
//
// Change: all MFMA GEMM k-loops move to a 3-buffer, 2-deep prefetch schedule
// with counted waits: s_waitcnt vmcnt(N) (N = newer in-flight stage's loads,
// never 0 in steady state) + raw s_barrier. Loads get 2 compute phases of
// cover and the in-flight prefetch is never drained (T4 / AITER pattern).
//  * k_moe_w13: 3 x 24KB buffers (72 KB LDS, still 2 blocks/CU).
//  * gemm128 core (w2, qkv, wo): 3 x 16KB buffers (48 KB -> 3 blocks/CU).
// ============================================================================

typedef unsigned short u16;
typedef unsigned int u32;
typedef __attribute__((ext_vector_type(8))) short s16x8;
typedef __attribute__((ext_vector_type(8))) _Float16 f16x8;
typedef __attribute__((ext_vector_type(4))) float f32x4;

#define S_LEN 2048
#define HDIM  1024
#define NHEAD 16
#define NKVH  4
#define HD    64
#define ISZ   3584
#define NEXP  8
#define NSLOT 4096
#define EPS_F 1e-5f
#define NEG_INF -1e30f
#define LOG2E 1.44269504f

__device__ __forceinline__ float bf2f(u16 u) {
    union { u32 i; float f; } c; c.i = ((u32)u) << 16; return c.f;
}
__device__ __forceinline__ u16 f2bf(float f) {
    union { float f; u32 i; } c; c.f = f;
    u32 r = (c.i + 0x7fffu + ((c.i >> 16) & 1u)) >> 16;
    return (u16)r;
}
__device__ __forceinline__ u16 f2h_bits(float f) {
    union { _Float16 h; u16 u; } c; c.h = (_Float16)f; return c.u;
}
__device__ __forceinline__ void async16(const u16* g, u16* l) {
    __builtin_amdgcn_global_load_lds(
        (const __attribute__((address_space(1))) void*)g,
        (__attribute__((address_space(3))) void*)l, 16, 0, 0);
}

// ---------------------------------------------------------------------------
__global__ void k_zero_ints(int* __restrict__ p, int n) {
    int i = blockIdx.x * blockDim.x + threadIdx.x;
    if (i < n) p[i] = 0;
}

// ---------------------------------------------------------------------------
__global__ __launch_bounds__(256)
void k_rmsnorm_bf(const float* __restrict__ x, const float* __restrict__ w,
                  u16* __restrict__ out) {
    int t = blockIdx.x;
    int tid = threadIdx.x;
    float4 v = ((const float4*)(x + (size_t)t * HDIM))[tid];
    float ss = v.x * v.x + v.y * v.y + v.z * v.z + v.w * v.w;
#pragma unroll
    for (int off = 32; off >= 1; off >>= 1) ss += __shfl_xor(ss, off, 64);
    __shared__ float red[4];
    if ((tid & 63) == 0) red[tid >> 6] = ss;
    __syncthreads();
    float tot = red[0] + red[1] + red[2] + red[3];
    float rstd = rsqrtf(tot * (1.0f / HDIM) + EPS_F);
    float4 wv = ((const float4*)w)[tid];
    uint2 pk;
    pk.x = (u32)f2bf(v.x * rstd * wv.x) | ((u32)f2bf(v.y * rstd * wv.y) << 16);
    pk.y = (u32)f2bf(v.z * rstd * wv.z) | ((u32)f2bf(v.w * rstd * wv.w) << 16);
    ((uint2*)(out + (size_t)t * HDIM))[tid] = pk;
}

// ---------------------------------------------------------------------------
// Transpose + convert: src fp32 [R][C] -> dst bf16 [C][R].
__global__ __launch_bounds__(256)
void k_cvt_t(const float* __restrict__ src, u16* __restrict__ dst,
             int R, int C, long long srcZ, long long dstZ) {
    const int z = blockIdx.z;
    src += (size_t)z * srcZ;
    dst += (size_t)z * dstZ;
    const int lane = threadIdx.x & 63, w = threadIdx.x >> 6;
    const int c = blockIdx.x * 64 + lane;
    const int r0 = blockIdx.y * 128 + w * 32;
    float v[32];
#pragma unroll
    for (int i = 0; i < 32; i++) v[i] = src[(size_t)(r0 + i) * C + c];
#pragma unroll
    for (int g = 0; g < 4; g++) {
        uint4 pk;
        pk.x = (u32)f2bf(v[g * 8 + 0]) | ((u32)f2bf(v[g * 8 + 1]) << 16);
        pk.y = (u32)f2bf(v[g * 8 + 2]) | ((u32)f2bf(v[g * 8 + 3]) << 16);
        pk.z = (u32)f2bf(v[g * 8 + 4]) | ((u32)f2bf(v[g * 8 + 5]) << 16);
        pk.w = (u32)f2bf(v[g * 8 + 6]) | ((u32)f2bf(v[g * 8 + 7]) << 16);
        *(uint4*)(&dst[(size_t)c * R + r0 + g * 8]) = pk;
    }
}

// ---------------------------------------------------------------------------
// Stage one 128x32 A-tile + 128x32 B-tile (bf16) into `buf` via async16.
// Per wave: 4 global_load_lds instructions.
__device__ __forceinline__ void stage32(const u16* __restrict__ A,
                                        const u16* __restrict__ Bt, int K,
                                        int rowA0, int rowAmax, int n0, int kc,
                                        u16* buf, int wid, int sr, int sc) {
#pragma unroll
    for (int t = 0; t < 2; t++) {
        int row = wid * 32 + t * 16 + sr;
        int ck = (sc ^ (row & 3)) << 3;
        int ra = rowA0 + row;
        if (ra > rowAmax) ra = rowAmax;
        u16* ldsA = buf + (wid * 32 + t * 16) * 32;
        async16(A + (size_t)ra * K + kc + ck, ldsA);
        async16(Bt + (size_t)(n0 + row) * K + kc + ck, ldsA + 4096);
    }
}

// 512-thread fused staging: A + B1 + B3 128x32 tiles (buffer 12288 elems).
// Per wave: 3 global_load_lds instructions.
__device__ __forceinline__ void stage_w13(const u16* __restrict__ A,
                                          const u16* __restrict__ B1,
                                          const u16* __restrict__ B3,
                                          int rowA0, int n0, int kc,
                                          u16* buf, int wid, int sr, int sc) {
    int row = wid * 16 + sr;              // 0..127, one row per (wave,lane/4)
    int ck = (sc ^ (row & 3)) << 3;
    int ra = rowA0 + row;
    if (ra > NSLOT - 1) ra = NSLOT - 1;
    u16* dst = buf + (wid * 16) * 32;     // wave-uniform LDS base
    async16(A  + (size_t)ra * HDIM + kc + ck, dst);
    async16(B1 + (size_t)(n0 + row) * HDIM + kc + ck, dst + 4096);
    async16(B3 + (size_t)(n0 + row) * HDIM + kc + ck, dst + 8192);
}

// ---------------------------------------------------------------------------
// Triple-buffered MFMA GEMM core with counted vmcnt: 2 stages in flight,
// s_waitcnt vmcnt(4) (= newer stage's 4 loads) + raw s_barrier per k-step.
// lds must be 24576 u16 (48 KB): three 8192-elem buffers (A @0, B @4096).
__device__ __forceinline__ void gemm128_tbuf(
    const u16* __restrict__ A, const u16* __restrict__ Bt, int K,
    int kbeg, int kend, int rowA0, int rowAmax, int n0,
    u16* lds, f32x4 acc[4][4]) {
    const int tid = threadIdx.x;
    const int lane = tid & 63, wid = tid >> 6;
    const int sr = lane >> 2, sc = lane & 3;
    const int ln = lane & 15, q = lane >> 4;
    const int wm = wid >> 1, wn = wid & 1;
    stage32(A, Bt, K, rowA0, rowAmax, n0, kbeg, lds, wid, sr, sc);
    if (kbeg + 32 < kend)
        stage32(A, Bt, K, rowA0, rowAmax, n0, kbeg + 32, lds + 8192,
                wid, sr, sc);
    int pp = 0;
    for (int kc = kbeg; kc < kend; kc += 32) {
        u16* cur = lds + pp * 8192;
        // wait: stage(kc) done; stage(kc+32)'s 4 loads may stay in flight
        if (kc + 32 < kend) asm volatile("s_waitcnt vmcnt(4)" ::: "memory");
        else                asm volatile("s_waitcnt vmcnt(0)" ::: "memory");
        __builtin_amdgcn_s_barrier();
        if (kc + 64 < kend) {
            int pn = pp + 2; if (pn >= 3) pn -= 3;
            stage32(A, Bt, K, rowA0, rowAmax, n0, kc + 64, lds + pn * 8192,
                    wid, sr, sc);
        }
        s16x8 af[4], bfv[4];
#pragma unroll
        for (int i = 0; i < 4; i++) {
            int ar = wm * 64 + i * 16 + ln;
            af[i] = *(const s16x8*)(cur + ar * 32 + ((q ^ (ar & 3)) << 3));
            int br = wn * 64 + i * 16 + ln;
            bfv[i] = *(const s16x8*)(cur + 4096 + br * 32 + ((q ^ (br & 3)) << 3));
        }
#pragma unroll
        for (int i = 0; i < 4; i++)
#pragma unroll
            for (int j = 0; j < 4; j++)
                acc[i][j] = __builtin_amdgcn_mfma_f32_16x16x32_bf16(
                    af[i], bfv[j], acc[i][j], 0, 0, 0);
        pp = (pp + 1 == 3) ? 0 : pp + 1;
    }
}

// ---------------------------------------------------------------------------
// Flat GEMM.  mode 0: fp32->F0 | 1: bf16->O16 | 2: fp32+RES->F0 |
//             3: qkv split -> F0(q fp32) F1(k fp32) O16(v fp16 bits)
__global__ __launch_bounds__(256, 3)
void k_gemm_bt(const u16* __restrict__ A, const u16* __restrict__ Bt,
               int M, int N, int K, int mode,
               float* __restrict__ F0, float* __restrict__ F1,
               const float* __restrict__ RES, u16* __restrict__ O16) {
    __shared__ u16 lds[24576];
    const int m0 = blockIdx.y * 128, n0 = blockIdx.x * 128;
    f32x4 acc[4][4];
#pragma unroll
    for (int i = 0; i < 4; i++)
#pragma unroll
        for (int j = 0; j < 4; j++) acc[i][j] = (f32x4){0.f, 0.f, 0.f, 0.f};
    gemm128_tbuf(A, Bt, K, 0, K, m0, M - 1, n0, lds, acc);
    const int lane = threadIdx.x & 63, wid = threadIdx.x >> 6;
    const int ln = lane & 15, q = lane >> 4, wm = wid >> 1, wn = wid & 1;
#pragma unroll
    for (int i = 0; i < 4; i++) {
#pragma unroll
        for (int r = 0; r < 4; r++) {
            int m = m0 + wm * 64 + i * 16 + q * 4 + r;
#pragma unroll
            for (int j = 0; j < 4; j++) {
                int n = n0 + wn * 64 + j * 16 + ln;
                float v = acc[i][j][r];
                if (mode == 0) {
                    F0[(size_t)m * N + n] = v;
                } else if (mode == 1) {
                    O16[(size_t)m * N + n] = f2bf(v);
                } else if (mode == 2) {
                    F0[(size_t)m * N + n] = v + RES[(size_t)m * N + n];
                } else {
                    if (n < 1024)       F0[(size_t)m * 1024 + n] = v;
                    else if (n < 1280)  F1[(size_t)m * 256 + (n - 1024)] = v;
                    else                O16[(size_t)m * 256 + (n - 1280)] = f2h_bits(v);
                }
            }
        }
    }
}

// ---------------------------------------------------------------------------
// Fused grouped MoE GEMM: He = silu(Xg @ w1^T) * (Xg @ w3^T), per expert.
// 512 threads / 8 waves, 128x128 tile of BOTH products, 3-buffer counted
// vmcnt pipeline (2 stages in flight, each wave 3 loads/stage).
__global__ __launch_bounds__(512, 4)
void k_moe_w13(const u16* __restrict__ Xg, const u16* __restrict__ W1T,
               const u16* __restrict__ W3T, u16* __restrict__ He,
               const int* __restrict__ offs, const int* __restrict__ mlist,
               const int* __restrict__ nitems) {
    __shared__ u16 lds[36864];            // 3 x (A 4096 + B1 4096 + B3 4096)
    const int NB = ISZ / 128;             // 28 n-blocks
    const int tot = nitems[0] * NB;
    const int tid = threadIdx.x;
    const int lane = tid & 63, wid = tid >> 6;
    const int sr = lane >> 2, sc = lane & 3;
    const int ln = lane & 15, q = lane >> 4;
    const int wm = wid >> 2, wn = wid & 3;  // 2 x 4 wave grid
    for (int it = blockIdx.x; it < tot; it += gridDim.x) {
        const int mi = it / NB, nb = it - mi * NB;
        const int em = mlist[mi];
        const int e = em >> 8, mb = em & 255;
        const int base = offs[e], cnt = offs[e + 1] - base;
        const int m0 = mb * 128, n0 = nb * 128;
        const int rowA0 = base + m0;
        const u16* B1 = W1T + (size_t)e * ISZ * HDIM;
        const u16* B3 = W3T + (size_t)e * ISZ * HDIM;
        f32x4 acc1[4][2], acc3[4][2];
#pragma unroll
        for (int i = 0; i < 4; i++)
#pragma unroll
            for (int j = 0; j < 2; j++) {
                acc1[i][j] = (f32x4){0.f, 0.f, 0.f, 0.f};
                acc3[i][j] = (f32x4){0.f, 0.f, 0.f, 0.f};
            }
        __syncthreads();  // all waves done with prev item's LDS + stores drain
        stage_w13(Xg, B1, B3, rowA0, n0, 0, lds, wid, sr, sc);
        stage_w13(Xg, B1, B3, rowA0, n0, 32, lds + 12288, wid, sr, sc);
        int pp = 0;
        for (int kc = 0; kc < HDIM; kc += 32) {
            u16* cur = lds + pp * 12288;
            // wait: stage(kc) done; stage(kc+32)'s 3 loads stay in flight
            if (kc + 32 < HDIM) asm volatile("s_waitcnt vmcnt(3)" ::: "memory");
            else                asm volatile("s_waitcnt vmcnt(0)" ::: "memory");
            __builtin_amdgcn_s_barrier();
            if (kc + 64 < HDIM) {
                int pn = pp + 2; if (pn >= 3) pn -= 3;
                stage_w13(Xg, B1, B3, rowA0, n0, kc + 64, lds + pn * 12288,
                          wid, sr, sc);
            }
            s16x8 af[4], b1f[2], b3f[2];
#pragma unroll
            for (int i = 0; i < 4; i++) {
                int ar = wm * 64 + i * 16 + ln;
                af[i] = *(const s16x8*)(cur + ar * 32 + ((q ^ (ar & 3)) << 3));
            }
#pragma unroll
            for (int j = 0; j < 2; j++) {
                int br = wn * 32 + j * 16 + ln;
                int bo = br * 32 + ((q ^ (br & 3)) << 3);
                b1f[j] = *(const s16x8*)(cur + 4096 + bo);
                b3f[j] = *(const s16x8*)(cur + 8192 + bo);
            }
#pragma unroll
            for (int i = 0; i < 4; i++)
#pragma unroll
                for (int j = 0; j < 2; j++) {
                    acc1[i][j] = __builtin_amdgcn_mfma_f32_16x16x32_bf16(
                        af[i], b1f[j], acc1[i][j], 0, 0, 0);
                    acc3[i][j] = __builtin_amdgcn_mfma_f32_16x16x32_bf16(
                        af[i], b3f[j], acc3[i][j], 0, 0, 0);
                }
            pp = (pp + 1 == 3) ? 0 : pp + 1;
        }
        // epilogue: silu(acc1) * acc3 -> He (bf16)
#pragma unroll
        for (int i = 0; i < 4; i++) {
#pragma unroll
            for (int r = 0; r < 4; r++) {
                int mloc = wm * 64 + i * 16 + q * 4 + r;
                if (m0 + mloc >= cnt) continue;
                size_t row = (size_t)(base + m0 + mloc);
#pragma unroll
                for (int j = 0; j < 2; j++) {
                    int n = n0 + wn * 32 + j * 16 + ln;
                    float v1 = acc1[i][j][r];
                    float v3 = acc3[i][j][r];
                    float s = v1 / (1.0f + expf(-v1));
                    He[row * ISZ + n] = f2bf(s * v3);
                }
            }
        }
    }
}

// ---------------------------------------------------------------------------
// MoE w2 GEMM, split-K=2, persistent worklist: item = mi*16 + (half*8 + nb).
__global__ __launch_bounds__(256, 3)
void k_moe_w2(const u16* __restrict__ He, const u16* __restrict__ W2T,
              float* __restrict__ OA, float* __restrict__ OB,
              const int* __restrict__ offs, const int* __restrict__ mlist,
              const int* __restrict__ nitems) {
    __shared__ u16 lds[24576];
    const int tot = nitems[0] * 16;
    const int lane = threadIdx.x & 63, wid = threadIdx.x >> 6;
    const int ln = lane & 15, q = lane >> 4, wm = wid >> 1, wn = wid & 1;
    for (int it = blockIdx.x; it < tot; it += gridDim.x) {
        const int mi = it >> 4, rr = it & 15;
        const int nb = rr & 7, half = rr >> 3;
        const int em = mlist[mi];
        const int e = em >> 8, mb = em & 255;
        const int base = offs[e], cnt = offs[e + 1] - base;
        const int m0 = mb * 128, n0 = nb * 128;
        const u16* Bt = W2T + (size_t)e * HDIM * ISZ;
        f32x4 acc[4][4];
#pragma unroll
        for (int i = 0; i < 4; i++)
#pragma unroll
            for (int j = 0; j < 4; j++) acc[i][j] = (f32x4){0.f, 0.f, 0.f, 0.f};
        __syncthreads();  // protect LDS from previous item's readers
        gemm128_tbuf(He, Bt, ISZ, half * (ISZ / 2), (half + 1) * (ISZ / 2),
                     base + m0, NSLOT - 1, n0, lds, acc);
        float* F0 = half ? OB : OA;
#pragma unroll
        for (int i = 0; i < 4; i++) {
#pragma unroll
            for (int r = 0; r < 4; r++) {
                int mloc = wm * 64 + i * 16 + q * 4 + r;
                if (m0 + mloc >= cnt) continue;
                size_t row = (size_t)(base + m0 + mloc);
#pragma unroll
                for (int j = 0; j < 4; j++) {
                    int n = n0 + wn * 64 + j * 16 + ln;
                    F0[row * HDIM + n] = acc[i][j][r];
                }
            }
        }
    }
}

// ---------------------------------------------------------------------------
// RoPE + convert to fp16 bits.
__global__ __launch_bounds__(256)
void k_rope_cvt(const float* __restrict__ q, const float* __restrict__ k,
                const int* __restrict__ pos, u16* __restrict__ qb2,
                u16* __restrict__ kb2) {
    int id = blockIdx.x * blockDim.x + threadIdx.x;
    int d = id & 31;
    int hh = (id >> 5) % (NHEAD + NKVH);
    int s = id / ((NHEAD + NKVH) * 32);
    float p = (float)pos[s];
    float inv = exp2f(-((float)(2 * d) / (float)HD) * log2f(1.0e6f));
    float ang = p * inv;
    float c = cosf(ang), sn = sinf(ang);
    const float* sp; u16* dp;
    if (hh < NHEAD) {
        sp = q + (size_t)s * (NHEAD * HD) + hh * HD;
        dp = qb2 + (size_t)s * (NHEAD * HD) + hh * HD;
    } else {
        sp = k + (size_t)s * (NKVH * HD) + (hh - NHEAD) * HD;
        dp = kb2 + (size_t)s * (NKVH * HD) + (hh - NHEAD) * HD;
    }
    float x1 = sp[d], x2 = sp[d + 32];
    dp[d]      = f2h_bits(x1 * c - x2 * sn);
    dp[d + 32] = f2h_bits(x2 * c + x1 * sn);
}

// ---------------------------------------------------------------------------
// MFMA flash attention (fp16 inputs, fp32 accumulate). Round-3-verified.
__global__ __launch_bounds__(256)
void k_attn_mfma(const u16* __restrict__ qb, const u16* __restrict__ kb,
                 const u16* __restrict__ vb, u16* __restrict__ ob) {
    __shared__ u16 Qs[64 * 64];
    __shared__ u16 Ks[64 * 64];
    __shared__ u16 Vt[64 * 64];
    __shared__ u16 Ps[64 * 64];
    const int qt = blockIdx.x, h = blockIdx.y, kvh = h >> 2;
    const int tid = threadIdx.x, lane = tid & 63, w = tid >> 6;
    const int ln = lane & 15, quad = lane >> 4;

#pragma unroll
    for (int p = 0; p < 2; p++) {
        int r = p * 32 + (tid >> 3), c = tid & 7;
        uint4 v = *(const uint4*)(qb + (size_t)(qt * 64 + r) * (NHEAD * HD) +
                                  h * HD + c * 8);
        *(uint4*)&Qs[r * 64 + ((c ^ (r & 7)) << 3)] = v;
    }

    float m_[4], l_[4];
    f32x4 Oa[4];
#pragma unroll
    for (int r = 0; r < 4; r++) { m_[r] = NEG_INF; l_[r] = 0.0f; }
#pragma unroll
    for (int nt = 0; nt < 4; nt++) Oa[nt] = (f32x4){0.f, 0.f, 0.f, 0.f};

    for (int kt = 0; kt <= qt; kt++) {
        __syncthreads();
#pragma unroll
        for (int p = 0; p < 2; p++) {
            int r = p * 32 + (tid >> 3), c = tid & 7;
            uint4 v = *(const uint4*)(kb + (size_t)(kt * 64 + r) * (NKVH * HD) +
                                      kvh * HD + c * 8);
            *(uint4*)&Ks[r * 64 + ((c ^ (r & 7)) << 3)] = v;
        }
        {
            int s = tid & 63;
#pragma unroll
            for (int half = 0; half < 2; half++) {
                int d0 = w * 16 + half * 8;
                uint4 v = *(const uint4*)(vb + (size_t)(kt * 64 + s) * (NKVH * HD) +
                                          kvh * HD + d0);
                u16 a[8];
                a[0] = (u16)(v.x & 0xffff); a[1] = (u16)(v.x >> 16);
                a[2] = (u16)(v.y & 0xffff); a[3] = (u16)(v.y >> 16);
                a[4] = (u16)(v.z & 0xffff); a[5] = (u16)(v.z >> 16);
                a[6] = (u16)(v.w & 0xffff); a[7] = (u16)(v.w >> 16);
#pragma unroll
                for (int j = 0; j < 8; j++) {
                    int d = d0 + j;
                    Vt[d * 64 + (((s >> 3) ^ (d & 7)) << 3) + (s & 7)] = a[j];
                }
            }
        }
        __syncthreads();

        f32x4 sc[4];
#pragma unroll
        for (int nt = 0; nt < 4; nt++) sc[nt] = (f32x4){0.f, 0.f, 0.f, 0.f};
#pragma unroll
        for (int ks = 0; ks < 2; ks++) {
            int arow = 16 * w + ln;
            f16x8 af = *(const f16x8*)&Qs[arow * 64 +
                                          (((ks * 4 + quad) ^ (arow & 7)) << 3)];
#pragma unroll
            for (int nt = 0; nt < 4; nt++) {
                int brow = nt * 16 + ln;
                f16x8 bf = *(const f16x8*)&Ks[brow * 64 +
                                              (((ks * 4 + quad) ^ (brow & 7)) << 3)];
                sc[nt] = __builtin_amdgcn_mfma_f32_16x16x32_f16(af, bf, sc[nt],
                                                                0, 0, 0);
            }
        }

        const bool diag = (kt == qt);
        float mt[4];
#pragma unroll
        for (int r = 0; r < 4; r++) {
            int qrow = quad * 4 + r + 16 * w;
#pragma unroll
            for (int nt = 0; nt < 4; nt++) {
                float s = sc[nt][r] * 0.125f;
                if (diag && (nt * 16 + ln) > qrow) s = NEG_INF;
                sc[nt][r] = s;
            }
            mt[r] = fmaxf(fmaxf(sc[0][r], sc[1][r]), fmaxf(sc[2][r], sc[3][r]));
        }
#pragma unroll
        for (int off = 8; off >= 1; off >>= 1)
#pragma unroll
            for (int r = 0; r < 4; r++)
                mt[r] = fmaxf(mt[r], __shfl_xor(mt[r], off, 64));

        float rs[4];
#pragma unroll
        for (int r = 0; r < 4; r++) {
            float mn = fmaxf(m_[r], mt[r]);
            float al = exp2f((m_[r] - mn) * LOG2E);
            m_[r] = mn;
            float acc0 = 0.0f;
#pragma unroll
            for (int nt = 0; nt < 4; nt++) {
                float pv = exp2f((sc[nt][r] - mn) * LOG2E);
                sc[nt][r] = pv;
                acc0 += pv;
            }
            rs[r] = acc0;
            l_[r] *= al;
#pragma unroll
            for (int nt = 0; nt < 4; nt++) Oa[nt][r] *= al;
        }
#pragma unroll
        for (int off = 8; off >= 1; off >>= 1)
#pragma unroll
            for (int r = 0; r < 4; r++) rs[r] += __shfl_xor(rs[r], off, 64);
#pragma unroll
        for (int r = 0; r < 4; r++) l_[r] += rs[r];

#pragma unroll
        for (int r = 0; r < 4; r++) {
            int row = 16 * w + quad * 4 + r;
#pragma unroll
            for (int nt = 0; nt < 4; nt++) {
                int ch = nt * 2 + (ln >> 3);
                Ps[row * 64 + ((ch ^ (row & 7)) << 3) + (ln & 7)] =
                    f2h_bits(sc[nt][r]);
            }
        }
        __syncthreads();

#pragma unroll
        for (int ks = 0; ks < 2; ks++) {
            int arow = 16 * w + ln;
            f16x8 pf = *(const f16x8*)&Ps[arow * 64 +
                                          (((ks * 4 + quad) ^ (arow & 7)) << 3)];
#pragma unroll
            for (int nt = 0; nt < 4; nt++) {
                int vrow = nt * 16 + ln;
                f16x8 vf = *(const f16x8*)&Vt[vrow * 64 +
                                              (((ks * 4 + quad) ^ (vrow & 7)) << 3)];
                Oa[nt] = __builtin_amdgcn_mfma_f32_16x16x32_f16(pf, vf, Oa[nt],
                                                                0, 0, 0);
            }
        }
    }

#pragma unroll
    for (int r = 0; r < 4; r++) {
        float inv = 1.0f / l_[r];
        int sg = qt * 64 + 16 * w + quad * 4 + r;
#pragma unroll
        for (int nt = 0; nt < 4; nt++) {
            int d = nt * 16 + ln;
            ob[(size_t)sg * HDIM + h * HD + d] = f2bf(Oa[nt][r] * inv);
        }
    }
}

// ---------------------------------------------------------------------------
__global__ __launch_bounds__(64)
void k_gate(const float* __restrict__ Hst, const float* __restrict__ PW,
            const float* __restrict__ GW, int* __restrict__ cnt,
            int* __restrict__ top_i, float* __restrict__ top_w) {
    int t = blockIdx.x;
    int lane = threadIdx.x;
    const float* hrow = Hst + (size_t)t * HDIM;
    float ss = 0.0f;
    float acc[NEXP] = {};
    for (int hh = lane; hh < HDIM; hh += 64) {
        float hv = hrow[hh];
        ss += hv * hv;
        float xw = hv * PW[hh];
        const float* g = GW + (size_t)hh * NEXP;
#pragma unroll
        for (int e = 0; e < NEXP; e++) acc[e] += xw * g[e];
    }
#pragma unroll
    for (int off = 32; off >= 1; off >>= 1) {
        ss += __shfl_xor(ss, off, 64);
#pragma unroll
        for (int e = 0; e < NEXP; e++) acc[e] += __shfl_xor(acc[e], off, 64);
    }
    if (lane == 0) {
        float rstd = rsqrtf(ss * (1.0f / HDIM) + EPS_F);
        int e0 = 0;
        for (int e = 1; e < NEXP; e++) if (acc[e] > acc[e0]) e0 = e;
        int e1 = (e0 == 0) ? 1 : 0;
        for (int e = 0; e < NEXP; e++)
            if (e != e0 && acc[e] > acc[e1]) e1 = e;
        float w0 = 1.0f / (1.0f + expf((acc[e1] - acc[e0]) * rstd));
        top_i[t * 2 + 0] = e0; top_i[t * 2 + 1] = e1;
        top_w[t * 2 + 0] = w0; top_w[t * 2 + 1] = 1.0f - w0;
        atomicAdd(&cnt[e0], 1);
        atomicAdd(&cnt[e1], 1);
    }
}

// prefix sums + worklist of (expert, m-block) items for the MoE GEMMs.
__global__ void k_prefix(const int* __restrict__ cnt, int* __restrict__ offs,
                         int* __restrict__ cur, int* __restrict__ mlist,
                         int* __restrict__ nitems) {
    if (blockIdx.x == 0 && threadIdx.x == 0) {
        int a = 0, idx = 0;
        for (int e = 0; e < NEXP; e++) {
            offs[e] = a; cur[e] = a;
            int c = cnt[e];
            int nmb = (c + 127) >> 7;
            for (int mb = 0; mb < nmb; mb++) mlist[idx++] = (e << 8) | mb;
            a += c;
        }
        offs[NEXP] = a;
        nitems[0] = idx;
    }
}

__global__ __launch_bounds__(256)
void k_fill(const int* __restrict__ top_i, int* __restrict__ cur,
            int* __restrict__ idxg, int* __restrict__ slot) {
    int t = blockIdx.x * blockDim.x + threadIdx.x;
    if (t >= S_LEN) return;
#pragma unroll
    for (int kk = 0; kk < 2; kk++) {
        int e = top_i[t * 2 + kk];
        int p = atomicAdd(&cur[e], 1);
        idxg[p] = t;
        slot[t * 2 + kk] = p;
    }
}

__global__ __launch_bounds__(256)
void k_gather(const u16* __restrict__ xnb, const int* __restrict__ idxg,
              u16* __restrict__ Xg) {
    int p = blockIdx.x;
    int t = idxg[p];
    const uint2* s = (const uint2*)(xnb + (size_t)t * HDIM);
    uint2* d = (uint2*)(Xg + (size_t)p * HDIM);
    d[threadIdx.x] = s[threadIdx.x];
}

__global__ __launch_bounds__(256)
void k_combine2(const float* __restrict__ OA, const float* __restrict__ OB,
                const int* __restrict__ slot, const float* __restrict__ top_w,
                float* __restrict__ out) {
    int t = blockIdx.x, tid = threadIdx.x;
    int s0 = slot[t * 2], s1 = slot[t * 2 + 1];
    float w0 = top_w[t * 2], w1 = top_w[t * 2 + 1];
    float4 a0 = ((const float4*)(OA + (size_t)s0 * HDIM))[tid];
    float4 b0 = ((const float4*)(OB + (size_t)s0 * HDIM))[tid];
    float4 a1 = ((const float4*)(OA + (size_t)s1 * HDIM))[tid];
    float4 b1 = ((const float4*)(OB + (size_t)s1 * HDIM))[tid];
    float4* o = (float4*)(out + (size_t)t * HDIM);
    float4 c = o[tid];
    c.x += w0 * (a0.x + b0.x) + w1 * (a1.x + b1.x);
    c.y += w0 * (a0.y + b0.y) + w1 * (a1.y + b1.y);
    c.z += w0 * (a0.z + b0.z) + w1 * (a1.z + b1.z);
    c.w += w0 * (a0.w + b0.w) + w1 * (a1.w + b1.w);
    o[tid] = c;
}

// ===========================================================================
extern "C" void kernel_launch(void* const* d_in, const int* in_sizes, int n_in,
                              void* d_out, int out_size, void* d_ws,
                              size_t ws_size, hipStream_t stream) {
    (void)in_sizes; (void)n_in; (void)out_size; (void)ws_size;
    const float* hidden = (const float*)d_in[0];
    const int*   pos    = (const int*)d_in[1];
    const float* wq     = (const float*)d_in[2];
    const float* wk     = (const float*)d_in[3];
    const float* wv     = (const float*)d_in[4];
    const float* wo     = (const float*)d_in[5];
    const float* innw   = (const float*)d_in[6];
    const float* postnw = (const float*)d_in[7];
    const float* gatew  = (const float*)d_in[8];
    const float* w1     = (const float*)d_in[9];
    const float* w3     = (const float*)d_in[10];
    const float* w2     = (const float*)d_in[11];
    float* out = (float*)d_out;

    // ---- workspace layout ----
    u16* w1t  = (u16*)d_ws;
    u16* w3t  = w1t + (size_t)NEXP * ISZ * HDIM;
    u16* w2t  = w3t + (size_t)NEXP * ISZ * HDIM;
    u16* qkvt = w2t + (size_t)NEXP * ISZ * HDIM;
    u16* wot  = qkvt + (size_t)1536 * HDIM;
    u16* xnb  = wot + (size_t)HDIM * HDIM;
    float* qbuf = (float*)(xnb + (size_t)S_LEN * HDIM);          // 2M fp32
    float* kbuf = qbuf + (size_t)S_LEN * HDIM;                   // 0.5M fp32
    u16* vb16   = (u16*)(kbuf + (size_t)S_LEN * NKVH * HD);      // 0.5M u16 (fp16)
    u16* qb2    = vb16 + (size_t)S_LEN * NKVH * HD;              // 2M u16 (fp16)
    u16* kb2    = qb2 + (size_t)S_LEN * HDIM;                    // 0.5M u16 (fp16)
    u16* attnb  = kb2 + (size_t)S_LEN * NKVH * HD;               // 2M u16 (bf16)
    float* oexpA = qbuf;  // overlay (16 MB): q/k/v/qb2/kb2 dead before w2
    u16* Xg  = attnb + (size_t)S_LEN * HDIM;
    u16* hg3 = Xg + (size_t)NSLOT * HDIM;                        // (unused now)
    u16* he  = hg3 + (size_t)NSLOT * ISZ;
    float* oexpB = (float*)(he + (size_t)NSLOT * ISZ);           // 16 MB
    int* ib  = (int*)(oexpB + (size_t)NSLOT * HDIM);
    int*   cnt   = ib;
    int*   offs  = ib + 16;
    int*   cur   = ib + 32;
    int*   top_i = ib + 64;
    int*   slot  = ib + 64 + 4096;
    int*   idxg  = ib + 64 + 8192;
    float* top_w = (float*)(ib + 64 + 12288);
    int*   mlist = ib + 64 + 16384;           // up to 128 items
    int*   nitems = ib + 64 + 16384 + 128;

    const long long HI = (long long)HDIM * ISZ;

    k_zero_ints<<<1, 64, 0, stream>>>(cnt, 64);
    k_rmsnorm_bf<<<S_LEN, 256, 0, stream>>>(hidden, innw, xnb);

    // weight transpose+convert (dst [N][K] bf16)
    k_cvt_t<<<dim3(16, 8, 1), 256, 0, stream>>>(wq, qkvt, 1024, 1024, 0, 0);
    k_cvt_t<<<dim3(4, 8, 1), 256, 0, stream>>>(wk, qkvt + (size_t)1024 * 1024, 1024, 256, 0, 0);
    k_cvt_t<<<dim3(4, 8, 1), 256, 0, stream>>>(wv, qkvt + (size_t)1280 * 1024, 1024, 256, 0, 0);
    k_cvt_t<<<dim3(16, 8, 1), 256, 0, stream>>>(wo, wot, 1024, 1024, 0, 0);
    k_cvt_t<<<dim3(56, 8, NEXP), 256, 0, stream>>>(w1, w1t, 1024, 3584, HI, HI);
    k_cvt_t<<<dim3(56, 8, NEXP), 256, 0, stream>>>(w3, w3t, 1024, 3584, HI, HI);
    k_cvt_t<<<dim3(16, 28, NEXP), 256, 0, stream>>>(w2, w2t, 3584, 1024, HI, HI);

    // qkv projection: q,k fp32 + v fp16
    k_gemm_bt<<<dim3(12, 16), 256, 0, stream>>>(xnb, qkvt, 2048, 1536, 1024, 3,
                                                qbuf, kbuf, nullptr, vb16);
    k_rope_cvt<<<(S_LEN * (NHEAD + NKVH) * 32) / 256, 256, 0, stream>>>(
        qbuf, kbuf, pos, qb2, kb2);
    k_attn_mfma<<<dim3(32, 16), 256, 0, stream>>>(qb2, kb2, vb16, attnb);
    // wo + residual -> d_out (h)
    k_gemm_bt<<<dim3(8, 16), 256, 0, stream>>>(attnb, wot, 2048, 1024, 1024, 2,
                                               out, nullptr, hidden, nullptr);
    // post-norm -> xnb ; gate from fp32 h (norm fused)
    k_rmsnorm_bf<<<S_LEN, 256, 0, stream>>>(out, postnw, xnb);
    k_gate<<<S_LEN, 64, 0, stream>>>(out, postnw, gatew, cnt, top_i, top_w);
    k_prefix<<<1, 1, 0, stream>>>(cnt, offs, cur, mlist, nitems);
    k_fill<<<S_LEN / 256, 256, 0, stream>>>(top_i, cur, idxg, slot);
    k_gather<<<NSLOT, 256, 0, stream>>>(xnb, idxg, Xg);

    // MoE: fused w1+w3 persistent (silu(x@w1)*(x@w3)), then w2 split-K=2
    k_moe_w13<<<dim3(512), 512, 0, stream>>>(Xg, w1t, w3t, he, offs, mlist,
                                             nitems);
    k_moe_w2<<<dim3(768), 256, 0, stream>>>(he, w2t, oexpA, oexpB, offs,
                                            mlist, nitems);
    k_combine2<<<S_LEN, 256, 0, stream>>>(oexpA, oexpB, slot, top_w, out);
}